// Round 4
// baseline (1187.653 us; speedup 1.0000x reference)
//
#include <hip/hip_runtime.h>
#include <hip/hip_bf16.h>

// ---------------------------------------------------------------------------
// FieldPredictionNetwork: MLP(512->1024->512->64, relu) -> fftn([B,64]) ->
// per-element piecewise-linear mode collapse (A+/A- fold of phase*w1*w0) ->
// complex lin1 + crelu -> (ifft64 folded into lin2) -> inverse 32768-pt FFT ->
// W_out GEMM -> output.
// Output layout decided at runtime from out_size:
//   out_size == 32768*128      -> real part only (complex64 cast to float32)
//   out_size == 32768*128*2    -> interleaved (re,im) float pairs
// B=32768, all batch-axis FFTs done as 128x256 two-stage direct DFTs in fp32.
// MLP GEMMs: bf16 MFMA with A hi/lo split (2 MFMA/acc) for accuracy.
// Peak workspace = 128 MB (MLP chunked over 2 batch halves).
// ---------------------------------------------------------------------------

#define PI2F 6.28318530717958647692f

typedef __attribute__((ext_vector_type(8))) short short8;
typedef __attribute__((ext_vector_type(4))) float f32x4;

__device__ __forceinline__ unsigned short f2bf(float f) {
  unsigned int u = __float_as_uint(f);
  u += 0x7fff + ((u >> 16) & 1);          // RN-even
  return (unsigned short)(u >> 16);
}
__device__ __forceinline__ float bf2f(unsigned short s) {
  return __uint_as_float(((unsigned int)s) << 16);
}

// ---------------------------------------------------------------------------
// GEMM: C = relu(A @ Bw^T + bias), A [M,K] f32, Bw [N,K] f32, C [M,N] f32.
// bf16 MFMA 16x16x32, A split hi/lo (2 MFMA per acc), W single bf16.
// Tile BM x BN, BK=32, 4 waves. LDS stride 40 shorts (pad: 2-way banks only).
// ---------------------------------------------------------------------------
template<int BM, int BN, int WM, int WN>
__global__ __launch_bounds__(256) void gemm_split(
    const float* __restrict__ A, const float* __restrict__ Bw,
    const float* __restrict__ bias, float* __restrict__ C,
    int M, int N, int K)
{
  constexpr int BK = 32;
  constexpr int LD = 40;                          // shorts; 80B row stride
  __shared__ __align__(16) unsigned short lAh[BM * LD];
  __shared__ __align__(16) unsigned short lAl[BM * LD];
  __shared__ __align__(16) unsigned short lBh[BN * LD];
  const int tid = threadIdx.x;
  const int lane = tid & 63;
  const int q = lane >> 4, lr = lane & 15;
  const int wave = tid >> 6;
  constexpr int WN_CNT = BN / WN;
  const int wm = (wave / WN_CNT) * WM;
  const int wn = (wave % WN_CNT) * WN;
  const size_t m0 = (size_t)blockIdx.x * BM;
  const size_t n0 = (size_t)blockIdx.y * BN;
  constexpr int MI = WM / 16, NI = WN / 16;
  f32x4 acc[MI][NI] = {};
  constexpr int A_CH = BM * BK / 4;               // float4 chunks
  constexpr int B_CH = BN * BK / 4;

  for (int k0 = 0; k0 < K; k0 += BK) {
    __syncthreads();
    for (int c = tid; c < A_CH; c += 256) {
      int row = c >> 3, c4 = c & 7;
      float4 v = *(const float4*)(A + (m0 + row) * K + k0 + c4 * 4);
      unsigned short h0 = f2bf(v.x), h1 = f2bf(v.y), h2 = f2bf(v.z), h3 = f2bf(v.w);
      unsigned short l0 = f2bf(v.x - bf2f(h0));
      unsigned short l1 = f2bf(v.y - bf2f(h1));
      unsigned short l2 = f2bf(v.z - bf2f(h2));
      unsigned short l3 = f2bf(v.w - bf2f(h3));
      uint2 hp, lp;
      hp.x = h0 | ((unsigned)h1 << 16); hp.y = h2 | ((unsigned)h3 << 16);
      lp.x = l0 | ((unsigned)l1 << 16); lp.y = l2 | ((unsigned)l3 << 16);
      *(uint2*)(lAh + row * LD + c4 * 4) = hp;
      *(uint2*)(lAl + row * LD + c4 * 4) = lp;
    }
    for (int c = tid; c < B_CH; c += 256) {
      int row = c >> 3, c4 = c & 7;
      float4 v = *(const float4*)(Bw + (n0 + row) * K + k0 + c4 * 4);
      uint2 hp;
      hp.x = f2bf(v.x) | ((unsigned)f2bf(v.y) << 16);
      hp.y = f2bf(v.z) | ((unsigned)f2bf(v.w) << 16);
      *(uint2*)(lBh + row * LD + c4 * 4) = hp;
    }
    __syncthreads();
    short8 ah[MI], al[MI], bh[NI];
    #pragma unroll
    for (int i = 0; i < MI; ++i) {
      ah[i] = *(const short8*)(lAh + (wm + i * 16 + lr) * LD + q * 8);
      al[i] = *(const short8*)(lAl + (wm + i * 16 + lr) * LD + q * 8);
    }
    #pragma unroll
    for (int j = 0; j < NI; ++j)
      bh[j] = *(const short8*)(lBh + (wn + j * 16 + lr) * LD + q * 8);
    #pragma unroll
    for (int i = 0; i < MI; ++i)
      #pragma unroll
      for (int j = 0; j < NI; ++j) {
        acc[i][j] = __builtin_amdgcn_mfma_f32_16x16x32_bf16(ah[i], bh[j], acc[i][j], 0, 0, 0);
        acc[i][j] = __builtin_amdgcn_mfma_f32_16x16x32_bf16(al[i], bh[j], acc[i][j], 0, 0, 0);
      }
  }
  // epilogue: D col = lane&15, row = quad*4 + reg  [verified mapping]
  #pragma unroll
  for (int i = 0; i < MI; ++i)
    #pragma unroll
    for (int j = 0; j < NI; ++j) {
      size_t col = n0 + wn + j * 16 + lr;
      float bv = bias[col];
      #pragma unroll
      for (int r = 0; r < 4; ++r) {
        size_t row = m0 + wm + i * 16 + q * 4 + r;
        float v = acc[i][j][r] + bv;
        C[row * N + col] = v > 0.f ? v : 0.f;
      }
    }
}

// ---------------------------------------------------------------------------
// Precompute A+/A-, Q = M@lin2_W (M = 64-pt IDFT matrix incl 1/64), b2c = M@lin2_b
// ---------------------------------------------------------------------------
__global__ __launch_bounds__(256) void precompute(
    const float* __restrict__ w0, const float* __restrict__ w1,
    const float* __restrict__ l2W, const float* __restrict__ l2b,
    float2* __restrict__ Ap, float2* __restrict__ Am,
    float2* __restrict__ Q, float2* __restrict__ b2c)
{
  const int t = threadIdx.x;
  if (t < 64) {
    float apx = 0, apy = 0, amx = 0, amy = 0;
    for (int m = 0; m < 32; ++m) {
      float s0 = w0[m * 64 + t];
      float cf = w1[m * 64 + t] * s0;
      float sn, cs; sincosf(PI2F * (float)m / 32.f, &sn, &cs);
      if (s0 > 0.f)      { apx += cs * cf; apy += sn * cf; }
      else if (s0 < 0.f) { amx += cs * cf; amy += sn * cf; }
    }
    Ap[t] = make_float2(apx, apy);
    Am[t] = make_float2(amx, amy);
    float bx = 0, by = 0;
    for (int k = 0; k < 64; ++k) {
      float sn, cs; sincosf(PI2F * (float)((t * k) & 63) / 64.f, &sn, &cs);
      float lb = l2b[k] * (1.f / 64.f);
      bx += cs * lb; by += sn * lb;
    }
    b2c[t] = make_float2(bx, by);
  }
  for (int e = t; e < 4096; e += 256) {
    int j = e >> 6, w = e & 63;
    float qx = 0, qy = 0;
    for (int k = 0; k < 64; ++k) {
      float sn, cs; sincosf(PI2F * (float)((j * k) & 63) / 64.f, &sn, &cs);
      float lw = l2W[k * 64 + w] * (1.f / 64.f);
      qx += cs * lw; qy += sn * lw;
    }
    Q[j * 64 + w] = make_float2(qx, qy);
  }
}

// ---------------------------------------------------------------------------
// DFT along axis1 (64-pt, forward): xh1[b,k] = sum_w x3[b,w] e^{-2pi i kw/64}
// ---------------------------------------------------------------------------
__global__ __launch_bounds__(256) void dft64_rows(
    const float* __restrict__ x3, float2* __restrict__ xh1)
{
  __shared__ float xt[64][64];
  __shared__ float2 tw[64];
  const int t = threadIdx.x;
  const size_t b0 = (size_t)blockIdx.x * 64;
  for (int it = 0; it < 16; ++it) {
    int idx = it * 256 + t;
    int r = idx >> 6, w = idx & 63;
    xt[r][w] = x3[(b0 + r) * 64 + w];
  }
  if (t < 64) {
    float sn, cs; sincosf(-PI2F * (float)t / 64.f, &sn, &cs);
    tw[t] = make_float2(cs, sn);
  }
  __syncthreads();
  const int k = t & 63, rg = t >> 6;
  float2 acc[16] = {};
  for (int w = 0; w < 64; ++w) {
    float2 tv = tw[(k * w) & 63];
    #pragma unroll
    for (int r = 0; r < 16; ++r) {
      float xv = xt[rg * 16 + r][w];     // broadcast read
      acc[r].x += xv * tv.x;
      acc[r].y += xv * tv.y;
    }
  }
  for (int r = 0; r < 16; ++r)
    xh1[(b0 + rg * 16 + r) * 64 + k] = acc[r];
}

// ---------------------------------------------------------------------------
// Batch-axis 32768-pt DFT, stage 1: 128-pt DFT over b1 (rows 256*b1+b2),
// times twiddle e^{s*2pi i b2*k1/32768}; writes T[k1][b2][w].
// Grid 512: blk = b2*2 + w-half.
// ---------------------------------------------------------------------------
template<int SIGN>
__global__ __launch_bounds__(256) void fft_stage1(
    const float2* __restrict__ X, float2* __restrict__ T)
{
  __shared__ float2 tile[128][32];
  __shared__ float2 tw[128];
  const int blk = blockIdx.x;
  const int b2 = blk >> 1, wh = (blk & 1) * 32;
  const int t = threadIdx.x;
  for (int it = 0; it < 16; ++it) {
    int idx = it * 256 + t;
    int b1 = idx >> 5, wi = idx & 31;
    tile[b1][wi] = X[((size_t)(b1 * 256 + b2)) * 64 + wh + wi];
  }
  if (t < 128) {
    float sn, cs; sincosf(SIGN * PI2F * (float)t / 128.f, &sn, &cs);
    tw[t] = make_float2(cs, sn);
  }
  __syncthreads();
  const int k1g = t >> 3, wg = t & 7;   // k1 = k1g*4+i, w = wh + wg*4+j
  float2 acc[4][4] = {};
  for (int b1 = 0; b1 < 128; ++b1) {
    float2 d[4];
    #pragma unroll
    for (int j = 0; j < 4; ++j) d[j] = tile[b1][wg * 4 + j];
    #pragma unroll
    for (int i = 0; i < 4; ++i) {
      float2 tv = tw[((k1g * 4 + i) * b1) & 127];
      #pragma unroll
      for (int j = 0; j < 4; ++j) {
        acc[i][j].x += d[j].x * tv.x - d[j].y * tv.y;
        acc[i][j].y += d[j].x * tv.y + d[j].y * tv.x;
      }
    }
  }
  #pragma unroll
  for (int i = 0; i < 4; ++i) {
    int k1 = k1g * 4 + i;
    float sn, cs;
    sincosf(SIGN * PI2F * (float)(b2 * k1) / 32768.f, &sn, &cs);
    #pragma unroll
    for (int j = 0; j < 4; ++j) {
      float2 a = acc[i][j];
      float2 o = make_float2(a.x * cs - a.y * sn, a.x * sn + a.y * cs);
      T[((size_t)k1 * 256 + b2) * 64 + wh + wg * 4 + j] = o;
    }
  }
}

// ---------------------------------------------------------------------------
// Stage 2: 256-pt DFT over b2 for fixed k1; X[k1 + 128*k2][w].
// Grid 512: blk = k1*4 + w-quarter. SCALE applies 1/32768 (inverse).
// ---------------------------------------------------------------------------
template<int SIGN, bool SCALE>
__global__ __launch_bounds__(256) void fft_stage2(
    const float2* __restrict__ T, float2* __restrict__ X)
{
  __shared__ float2 tile[256][16];
  __shared__ float2 tw[256];
  const int blk = blockIdx.x;
  const int k1 = blk >> 2, wq = (blk & 3) * 16;
  const int t = threadIdx.x;
  for (int it = 0; it < 16; ++it) {
    int idx = it * 256 + t;
    int r2 = idx >> 4, wi = idx & 15;
    tile[r2][wi] = T[((size_t)k1 * 256 + r2) * 64 + wq + wi];
  }
  {
    float sn, cs; sincosf(SIGN * PI2F * (float)t / 256.f, &sn, &cs);
    tw[t] = make_float2(cs, sn);
  }
  __syncthreads();
  const int k2g = t >> 2, wg = t & 3;   // k2 = k2g*4+i, w = wq + wg*4+j
  float2 acc[4][4] = {};
  for (int r2 = 0; r2 < 256; ++r2) {
    float2 d[4];
    #pragma unroll
    for (int j = 0; j < 4; ++j) d[j] = tile[r2][wg * 4 + j];
    #pragma unroll
    for (int i = 0; i < 4; ++i) {
      float2 tv = tw[((k2g * 4 + i) * r2) & 255];
      #pragma unroll
      for (int j = 0; j < 4; ++j) {
        acc[i][j].x += d[j].x * tv.x - d[j].y * tv.y;
        acc[i][j].y += d[j].x * tv.y + d[j].y * tv.x;
      }
    }
  }
  const float sc = SCALE ? (1.f / 32768.f) : 1.f;
  #pragma unroll
  for (int i = 0; i < 4; ++i) {
    size_t row = (size_t)(k1 + 128 * (k2g * 4 + i));
    #pragma unroll
    for (int j = 0; j < 4; ++j) {
      float2 a = acc[i][j];
      X[row * 64 + wq + wg * 4 + j] = make_float2(a.x * sc, a.y * sc);
    }
  }
}

// ---------------------------------------------------------------------------
// Pointwise A+/- fold, z = crelu(y@lin1^T + lin1_b), u = z@Q^T + b2c.
// 32 rows per block (LDS 32KB), grid 1024.
// ---------------------------------------------------------------------------
__global__ __launch_bounds__(256) void pw_lin(
    const float2* __restrict__ xh,
    const float2* __restrict__ Ap, const float2* __restrict__ Am,
    const float* __restrict__ l1W, const float* __restrict__ l1b,
    const float2* __restrict__ Q, const float2* __restrict__ b2c,
    float2* __restrict__ u)
{
  __shared__ float2 yt[32][64];
  __shared__ float2 zt[32][64];
  const int t = threadIdx.x;
  const size_t b0 = (size_t)blockIdx.x * 32;
  for (int it = 0; it < 8; ++it) {
    int idx = it * 256 + t;
    int r = idx >> 6, w = idx & 63;
    float2 xv = xh[(b0 + r) * 64 + w];
    float2 Aa = (xv.x >= 0.f) ? Ap[w] : Am[w];
    float2 Ab = (xv.y >= 0.f) ? Ap[w] : Am[w];
    float c1r = xv.x * Aa.x, c1i = xv.x * Aa.y;
    float c2r = xv.y * Ab.x, c2i = xv.y * Ab.y;
    yt[r][w] = make_float2(c1r - c2i, c1i + c2r);   // y = c1 + i*c2
  }
  __syncthreads();
  {
    const int n = t & 63, rg = t >> 6;              // 8 rows per thread
    float2 acc[8] = {};
    for (int w = 0; w < 64; ++w) {
      float lw = l1W[n * 64 + w];
      #pragma unroll
      for (int r = 0; r < 8; ++r) {
        float2 yv = yt[rg * 8 + r][w];              // broadcast
        acc[r].x += yv.x * lw;
        acc[r].y += yv.y * lw;
      }
    }
    float bb = l1b[n];
    #pragma unroll
    for (int r = 0; r < 8; ++r) {
      float zr = acc[r].x + bb; zr = zr > 0.f ? zr : 0.f;
      float zi = acc[r].y;      zi = zi > 0.f ? zi : 0.f;
      zt[rg * 8 + r][n] = make_float2(zr, zi);
    }
  }
  __syncthreads();
  {
    const int j = t & 63, rg = t >> 6;
    float2 acc[8] = {};
    for (int w = 0; w < 64; ++w) {
      float2 qv = Q[j * 64 + w];
      #pragma unroll
      for (int r = 0; r < 8; ++r) {
        float2 zv = zt[rg * 8 + r][w];              // broadcast
        acc[r].x += zv.x * qv.x - zv.y * qv.y;
        acc[r].y += zv.x * qv.y + zv.y * qv.x;
      }
    }
    float2 bc = b2c[j];
    #pragma unroll
    for (int r = 0; r < 8; ++r)
      u[(b0 + rg * 8 + r) * 64 + j] = make_float2(acc[r].x + bc.x, acc[r].y + bc.y);
  }
}

// ---------------------------------------------------------------------------
// out[b,f] = sum_j v[b,j]*Wout[f,j] + bout[f] (real bias).
// MODE 0: store real part only (float,   out_size = B*128 elements).
// MODE 1: store interleaved (re,im)     (float2, out_size = B*128*2 floats).
// ---------------------------------------------------------------------------
template<int MODE>
__global__ __launch_bounds__(256) void final_out(
    const float2* __restrict__ v, const float* __restrict__ Wout,
    const float* __restrict__ bout, float* __restrict__ out)
{
  __shared__ float2 vt[64][64];
  const int t = threadIdx.x;
  const size_t b0 = (size_t)blockIdx.x * 64;
  for (int it = 0; it < 16; ++it) {
    int idx = it * 256 + t;
    int r = idx >> 6, w = idx & 63;
    vt[r][w] = v[(b0 + r) * 64 + w];
  }
  __syncthreads();
  const int f = t & 127, rg = t >> 7;   // 32 rows per thread
  float2 acc[32] = {};
  for (int j = 0; j < 64; ++j) {
    float wv = Wout[f * 64 + j];
    #pragma unroll
    for (int r = 0; r < 32; ++r) {
      float2 vv = vt[rg * 32 + r][j];   // broadcast
      acc[r].x += vv.x * wv;
      acc[r].y += vv.y * wv;
    }
  }
  float bb = bout[f];
  #pragma unroll
  for (int r = 0; r < 32; ++r) {
    size_t idx = (b0 + rg * 32 + r) * 128 + f;
    if (MODE == 0) {
      out[idx] = acc[r].x + bb;
    } else {
      ((float2*)out)[idx] = make_float2(acc[r].x + bb, acc[r].y);
    }
  }
}

// ---------------------------------------------------------------------------
extern "C" void kernel_launch(void* const* d_in, const int* in_sizes, int n_in,
                              void* d_out, int out_size, void* d_ws, size_t ws_size,
                              hipStream_t stream)
{
  (void)in_sizes; (void)n_in; (void)ws_size;
  const float* geom = (const float*)d_in[0];
  const float* Win  = (const float*)d_in[1];
  const float* bin  = (const float*)d_in[2];
  const float* Wh1  = (const float*)d_in[3];
  const float* bh1  = (const float*)d_in[4];
  const float* Wh2  = (const float*)d_in[5];
  const float* bh2  = (const float*)d_in[6];
  const float* w0   = (const float*)d_in[7];
  const float* w1   = (const float*)d_in[8];
  const float* l1W  = (const float*)d_in[9];
  const float* l1b  = (const float*)d_in[10];
  const float* l2W  = (const float*)d_in[11];
  const float* l2b  = (const float*)d_in[12];
  const float* Wout = (const float*)d_in[13];
  const float* bout = (const float*)d_in[14];

  char* ws = (char*)d_ws;
  const size_t MB = 1048576ull;
  // Peak workspace = 128 MB:
  //   [0,64MB)    x2 [32768,512] f32 (full)
  //   [64,128MB)  x1-half [16384,1024] f32 during MLP chunks;
  //               afterwards reused: x3 @64MB (8MB), S0 @72MB (16MB),
  //               S1 @88MB (16MB), consts @104MB (~34KB).
  float*  x2  = (float*)(ws);
  float*  x1h = (float*)(ws + 64 * MB);
  float*  x3  = (float*)(ws + 64 * MB);
  float2* S0  = (float2*)(ws + 72 * MB);
  float2* S1  = (float2*)(ws + 88 * MB);
  float2* Ap  = (float2*)(ws + 104 * MB);
  float2* Am  = (float2*)(ws + 104 * MB + 512);
  float2* b2c = (float2*)(ws + 104 * MB + 1024);
  float2* Q   = (float2*)(ws + 104 * MB + 1536);

  // MLP encoder, chunked over 2 batch halves (M_half = 16384 = 128*128)
  for (int c = 0; c < 2; ++c) {
    const float* gchunk = geom + (size_t)c * 16384 * 512;
    float* x2chunk = x2 + (size_t)c * 16384 * 512;
    gemm_split<128,128,64,64><<<dim3(128, 8), 256, 0, stream>>>(gchunk, Win, bin, x1h, 16384, 1024, 512);
    gemm_split<128,128,64,64><<<dim3(128, 4), 256, 0, stream>>>(x1h, Wh1, bh1, x2chunk, 16384, 512, 1024);
  }
  gemm_split<128, 64,64,32><<<dim3(256, 1), 256, 0, stream>>>(x2, Wh2, bh2, x3, 32768, 64, 512);
  // constants (A+/-, Q = M@lin2_W, b2c = M@lin2_b)
  precompute<<<1, 256, 0, stream>>>(w0, w1, l2W, l2b, Ap, Am, Q, b2c);
  // fftn: 64-pt along axis1, then 32768-pt along axis0 (two-stage)
  dft64_rows<<<512, 256, 0, stream>>>(x3, S0);
  fft_stage1<-1><<<512, 256, 0, stream>>>(S0, S1);
  fft_stage2<-1, false><<<512, 256, 0, stream>>>(S1, S0);
  // mode collapse + lin1 + crelu + (ifft64-folded lin2)
  pw_lin<<<1024, 256, 0, stream>>>(S0, Ap, Am, l1W, l1b, Q, b2c, S1);
  // inverse 32768-pt along axis0 (with 1/32768)
  fft_stage1<1><<<512, 256, 0, stream>>>(S1, S0);
  fft_stage2<1, true><<<512, 256, 0, stream>>>(S0, S1);
  // W_out + b_out -> output (layout per out_size; see header comment)
  if (out_size >= 8388608) {
    final_out<1><<<512, 256, 0, stream>>>(S1, Wout, bout, (float*)d_out);
  } else {
    final_out<0><<<512, 256, 0, stream>>>(S1, Wout, bout, (float*)d_out);
  }
}

// Round 5
// 1004.569 us; speedup vs baseline: 1.1823x; 1.1823x over previous
//
#include <hip/hip_runtime.h>
#include <hip/hip_bf16.h>

// ---------------------------------------------------------------------------
// FieldPredictionNetwork: MLP(512->1024->512->64, relu) -> fftn([B,64]) ->
// per-element piecewise-linear mode collapse (A+/A- fold of phase*w1*w0) ->
// complex lin1 + crelu -> (ifft64 folded into lin2) -> inverse 32768-pt FFT ->
// W_out GEMM -> output (real part only when out_size==B*128; interleaved
// otherwise). B=32768. Batch-axis FFTs: 128x256 two-stage direct DFT, fp32.
// R5: precompute parallelized (was 180us single-block); GEMM A hi/lo split
// dropped (measured 9x accuracy margin in R4) -> plain bf16 MFMA, half the
// MFMA work and staging VALU.
// ---------------------------------------------------------------------------

#define PI2F 6.28318530717958647692f

typedef __attribute__((ext_vector_type(8))) short short8;
typedef __attribute__((ext_vector_type(4))) float f32x4;

__device__ __forceinline__ unsigned int pack_bf16x2(float a, float b) {
  __hip_bfloat162 h = __float22bfloat162_rn(make_float2(a, b));  // v_cvt_pk_bf16_f32
  return *(unsigned int*)&h;
}

// ---------------------------------------------------------------------------
// GEMM: C = relu(A @ Bw^T + bias), A [M,K] f32, Bw [N,K] f32, C [M,N] f32.
// bf16 MFMA 16x16x32. Tile BM x BN, BK=32, 4 waves. LDS stride 40 shorts.
// ---------------------------------------------------------------------------
template<int BM, int BN, int WM, int WN>
__global__ __launch_bounds__(256) void gemm_bf16(
    const float* __restrict__ A, const float* __restrict__ Bw,
    const float* __restrict__ bias, float* __restrict__ C,
    int M, int N, int K)
{
  constexpr int BK = 32;
  constexpr int LD = 40;                          // shorts; 80B row stride
  __shared__ __align__(16) unsigned short lA[BM * LD];
  __shared__ __align__(16) unsigned short lB[BN * LD];
  const int tid = threadIdx.x;
  const int lane = tid & 63;
  const int q = lane >> 4, lr = lane & 15;
  const int wave = tid >> 6;
  constexpr int WN_CNT = BN / WN;
  const int wm = (wave / WN_CNT) * WM;
  const int wn = (wave % WN_CNT) * WN;
  const size_t m0 = (size_t)blockIdx.x * BM;
  const size_t n0 = (size_t)blockIdx.y * BN;
  constexpr int MI = WM / 16, NI = WN / 16;
  f32x4 acc[MI][NI] = {};
  constexpr int A_CH = BM * BK / 4;               // float4 chunks
  constexpr int B_CH = BN * BK / 4;

  for (int k0 = 0; k0 < K; k0 += BK) {
    __syncthreads();
    for (int c = tid; c < A_CH; c += 256) {
      int row = c >> 3, c4 = c & 7;
      float4 v = *(const float4*)(A + (m0 + row) * K + k0 + c4 * 4);
      uint2 hp;
      hp.x = pack_bf16x2(v.x, v.y);
      hp.y = pack_bf16x2(v.z, v.w);
      *(uint2*)(lA + row * LD + c4 * 4) = hp;
    }
    for (int c = tid; c < B_CH; c += 256) {
      int row = c >> 3, c4 = c & 7;
      float4 v = *(const float4*)(Bw + (n0 + row) * K + k0 + c4 * 4);
      uint2 hp;
      hp.x = pack_bf16x2(v.x, v.y);
      hp.y = pack_bf16x2(v.z, v.w);
      *(uint2*)(lB + row * LD + c4 * 4) = hp;
    }
    __syncthreads();
    short8 af[MI], bf[NI];
    #pragma unroll
    for (int i = 0; i < MI; ++i)
      af[i] = *(const short8*)(lA + (wm + i * 16 + lr) * LD + q * 8);
    #pragma unroll
    for (int j = 0; j < NI; ++j)
      bf[j] = *(const short8*)(lB + (wn + j * 16 + lr) * LD + q * 8);
    #pragma unroll
    for (int i = 0; i < MI; ++i)
      #pragma unroll
      for (int j = 0; j < NI; ++j)
        acc[i][j] = __builtin_amdgcn_mfma_f32_16x16x32_bf16(af[i], bf[j], acc[i][j], 0, 0, 0);
  }
  // epilogue: D col = lane&15, row = quad*4 + reg  [verified mapping]
  #pragma unroll
  for (int i = 0; i < MI; ++i)
    #pragma unroll
    for (int j = 0; j < NI; ++j) {
      size_t col = n0 + wn + j * 16 + lr;
      float bv = bias[col];
      #pragma unroll
      for (int r = 0; r < 4; ++r) {
        size_t row = m0 + wm + i * 16 + q * 4 + r;
        float v = acc[i][j][r] + bv;
        C[row * N + col] = v > 0.f ? v : 0.f;
      }
    }
}

// ---------------------------------------------------------------------------
// Precompute (parallel): block 0 -> Ap/Am/b2c; blocks 1..16 -> Q (256 ea).
// Q = M@lin2_W (M = 64-pt IDFT matrix incl 1/64), b2c = M@lin2_b.
// ---------------------------------------------------------------------------
__global__ __launch_bounds__(256) void precompute(
    const float* __restrict__ w0, const float* __restrict__ w1,
    const float* __restrict__ l2W, const float* __restrict__ l2b,
    float2* __restrict__ Ap, float2* __restrict__ Am,
    float2* __restrict__ Q, float2* __restrict__ b2c)
{
  const int t = threadIdx.x;
  const int blk = blockIdx.x;
  if (blk == 0) {
    if (t < 64) {
      float apx = 0, apy = 0, amx = 0, amy = 0;
      for (int m = 0; m < 32; ++m) {
        float s0 = w0[m * 64 + t];
        float cf = w1[m * 64 + t] * s0;
        float sn, cs; sincosf(PI2F * (float)m / 32.f, &sn, &cs);
        if (s0 > 0.f)      { apx += cs * cf; apy += sn * cf; }
        else if (s0 < 0.f) { amx += cs * cf; amy += sn * cf; }
      }
      Ap[t] = make_float2(apx, apy);
      Am[t] = make_float2(amx, amy);
      float bx = 0, by = 0;
      for (int k = 0; k < 64; ++k) {
        float sn, cs; sincosf(PI2F * (float)((t * k) & 63) / 64.f, &sn, &cs);
        float lb = l2b[k] * (1.f / 64.f);
        bx += cs * lb; by += sn * lb;
      }
      b2c[t] = make_float2(bx, by);
    }
  } else {
    int e = (blk - 1) * 256 + t;                  // e in [0,4096)
    int j = e >> 6, w = e & 63;
    float qx = 0, qy = 0;
    for (int k = 0; k < 64; ++k) {
      float sn, cs; sincosf(PI2F * (float)((j * k) & 63) / 64.f, &sn, &cs);
      float lw = l2W[k * 64 + w] * (1.f / 64.f);
      qx += cs * lw; qy += sn * lw;
    }
    Q[j * 64 + w] = make_float2(qx, qy);
  }
}

// ---------------------------------------------------------------------------
// DFT along axis1 (64-pt, forward): xh1[b,k] = sum_w x3[b,w] e^{-2pi i kw/64}
// ---------------------------------------------------------------------------
__global__ __launch_bounds__(256) void dft64_rows(
    const float* __restrict__ x3, float2* __restrict__ xh1)
{
  __shared__ float xt[64][64];
  __shared__ float2 tw[64];
  const int t = threadIdx.x;
  const size_t b0 = (size_t)blockIdx.x * 64;
  for (int it = 0; it < 16; ++it) {
    int idx = it * 256 + t;
    int r = idx >> 6, w = idx & 63;
    xt[r][w] = x3[(b0 + r) * 64 + w];
  }
  if (t < 64) {
    float sn, cs; sincosf(-PI2F * (float)t / 64.f, &sn, &cs);
    tw[t] = make_float2(cs, sn);
  }
  __syncthreads();
  const int k = t & 63, rg = t >> 6;
  float2 acc[16] = {};
  for (int w = 0; w < 64; ++w) {
    float2 tv = tw[(k * w) & 63];
    #pragma unroll
    for (int r = 0; r < 16; ++r) {
      float xv = xt[rg * 16 + r][w];     // broadcast read
      acc[r].x += xv * tv.x;
      acc[r].y += xv * tv.y;
    }
  }
  for (int r = 0; r < 16; ++r)
    xh1[(b0 + rg * 16 + r) * 64 + k] = acc[r];
}

// ---------------------------------------------------------------------------
// Batch-axis 32768-pt DFT, stage 1: 128-pt DFT over b1 (rows 256*b1+b2),
// times twiddle e^{s*2pi i b2*k1/32768}; writes T[k1][b2][w].
// Grid 512: blk = b2*2 + w-half.
// ---------------------------------------------------------------------------
template<int SIGN>
__global__ __launch_bounds__(256) void fft_stage1(
    const float2* __restrict__ X, float2* __restrict__ T)
{
  __shared__ float2 tile[128][32];
  __shared__ float2 tw[128];
  const int blk = blockIdx.x;
  const int b2 = blk >> 1, wh = (blk & 1) * 32;
  const int t = threadIdx.x;
  for (int it = 0; it < 16; ++it) {
    int idx = it * 256 + t;
    int b1 = idx >> 5, wi = idx & 31;
    tile[b1][wi] = X[((size_t)(b1 * 256 + b2)) * 64 + wh + wi];
  }
  if (t < 128) {
    float sn, cs; sincosf(SIGN * PI2F * (float)t / 128.f, &sn, &cs);
    tw[t] = make_float2(cs, sn);
  }
  __syncthreads();
  const int k1g = t >> 3, wg = t & 7;   // k1 = k1g*4+i, w = wh + wg*4+j
  float2 acc[4][4] = {};
  for (int b1 = 0; b1 < 128; ++b1) {
    float2 d[4];
    #pragma unroll
    for (int j = 0; j < 4; ++j) d[j] = tile[b1][wg * 4 + j];
    #pragma unroll
    for (int i = 0; i < 4; ++i) {
      float2 tv = tw[((k1g * 4 + i) * b1) & 127];
      #pragma unroll
      for (int j = 0; j < 4; ++j) {
        acc[i][j].x += d[j].x * tv.x - d[j].y * tv.y;
        acc[i][j].y += d[j].x * tv.y + d[j].y * tv.x;
      }
    }
  }
  #pragma unroll
  for (int i = 0; i < 4; ++i) {
    int k1 = k1g * 4 + i;
    float sn, cs;
    sincosf(SIGN * PI2F * (float)(b2 * k1) / 32768.f, &sn, &cs);
    #pragma unroll
    for (int j = 0; j < 4; ++j) {
      float2 a = acc[i][j];
      float2 o = make_float2(a.x * cs - a.y * sn, a.x * sn + a.y * cs);
      T[((size_t)k1 * 256 + b2) * 64 + wh + wg * 4 + j] = o;
    }
  }
}

// ---------------------------------------------------------------------------
// Stage 2: 256-pt DFT over b2 for fixed k1; X[k1 + 128*k2][w].
// Grid 512: blk = k1*4 + w-quarter. SCALE applies 1/32768 (inverse).
// ---------------------------------------------------------------------------
template<int SIGN, bool SCALE>
__global__ __launch_bounds__(256) void fft_stage2(
    const float2* __restrict__ T, float2* __restrict__ X)
{
  __shared__ float2 tile[256][16];
  __shared__ float2 tw[256];
  const int blk = blockIdx.x;
  const int k1 = blk >> 2, wq = (blk & 3) * 16;
  const int t = threadIdx.x;
  for (int it = 0; it < 16; ++it) {
    int idx = it * 256 + t;
    int r2 = idx >> 4, wi = idx & 15;
    tile[r2][wi] = T[((size_t)k1 * 256 + r2) * 64 + wq + wi];
  }
  {
    float sn, cs; sincosf(SIGN * PI2F * (float)t / 256.f, &sn, &cs);
    tw[t] = make_float2(cs, sn);
  }
  __syncthreads();
  const int k2g = t >> 2, wg = t & 3;   // k2 = k2g*4+i, w = wq + wg*4+j
  float2 acc[4][4] = {};
  for (int r2 = 0; r2 < 256; ++r2) {
    float2 d[4];
    #pragma unroll
    for (int j = 0; j < 4; ++j) d[j] = tile[r2][wg * 4 + j];
    #pragma unroll
    for (int i = 0; i < 4; ++i) {
      float2 tv = tw[((k2g * 4 + i) * r2) & 255];
      #pragma unroll
      for (int j = 0; j < 4; ++j) {
        acc[i][j].x += d[j].x * tv.x - d[j].y * tv.y;
        acc[i][j].y += d[j].x * tv.y + d[j].y * tv.x;
      }
    }
  }
  const float sc = SCALE ? (1.f / 32768.f) : 1.f;
  #pragma unroll
  for (int i = 0; i < 4; ++i) {
    size_t row = (size_t)(k1 + 128 * (k2g * 4 + i));
    #pragma unroll
    for (int j = 0; j < 4; ++j) {
      float2 a = acc[i][j];
      X[row * 64 + wq + wg * 4 + j] = make_float2(a.x * sc, a.y * sc);
    }
  }
}

// ---------------------------------------------------------------------------
// Pointwise A+/- fold, z = crelu(y@lin1^T + lin1_b), u = z@Q^T + b2c.
// 32 rows per block (LDS 32KB), grid 1024.
// ---------------------------------------------------------------------------
__global__ __launch_bounds__(256) void pw_lin(
    const float2* __restrict__ xh,
    const float2* __restrict__ Ap, const float2* __restrict__ Am,
    const float* __restrict__ l1W, const float* __restrict__ l1b,
    const float2* __restrict__ Q, const float2* __restrict__ b2c,
    float2* __restrict__ u)
{
  __shared__ float2 yt[32][64];
  __shared__ float2 zt[32][64];
  const int t = threadIdx.x;
  const size_t b0 = (size_t)blockIdx.x * 32;
  for (int it = 0; it < 8; ++it) {
    int idx = it * 256 + t;
    int r = idx >> 6, w = idx & 63;
    float2 xv = xh[(b0 + r) * 64 + w];
    float2 Aa = (xv.x >= 0.f) ? Ap[w] : Am[w];
    float2 Ab = (xv.y >= 0.f) ? Ap[w] : Am[w];
    float c1r = xv.x * Aa.x, c1i = xv.x * Aa.y;
    float c2r = xv.y * Ab.x, c2i = xv.y * Ab.y;
    yt[r][w] = make_float2(c1r - c2i, c1i + c2r);   // y = c1 + i*c2
  }
  __syncthreads();
  {
    const int n = t & 63, rg = t >> 6;              // 8 rows per thread
    float2 acc[8] = {};
    for (int w = 0; w < 64; ++w) {
      float lw = l1W[n * 64 + w];
      #pragma unroll
      for (int r = 0; r < 8; ++r) {
        float2 yv = yt[rg * 8 + r][w];              // broadcast
        acc[r].x += yv.x * lw;
        acc[r].y += yv.y * lw;
      }
    }
    float bb = l1b[n];
    #pragma unroll
    for (int r = 0; r < 8; ++r) {
      float zr = acc[r].x + bb; zr = zr > 0.f ? zr : 0.f;
      float zi = acc[r].y;      zi = zi > 0.f ? zi : 0.f;
      zt[rg * 8 + r][n] = make_float2(zr, zi);
    }
  }
  __syncthreads();
  {
    const int j = t & 63, rg = t >> 6;
    float2 acc[8] = {};
    for (int w = 0; w < 64; ++w) {
      float2 qv = Q[j * 64 + w];
      #pragma unroll
      for (int r = 0; r < 8; ++r) {
        float2 zv = zt[rg * 8 + r][w];              // broadcast
        acc[r].x += zv.x * qv.x - zv.y * qv.y;
        acc[r].y += zv.x * qv.y + zv.y * qv.x;
      }
    }
    float2 bc = b2c[j];
    #pragma unroll
    for (int r = 0; r < 8; ++r)
      u[(b0 + rg * 8 + r) * 64 + j] = make_float2(acc[r].x + bc.x, acc[r].y + bc.y);
  }
}

// ---------------------------------------------------------------------------
// out[b,f] = sum_j v[b,j]*Wout[f,j] + bout[f] (real bias).
// MODE 0: store real part only (float,   out_size = B*128 elements).
// MODE 1: store interleaved (re,im)     (float2, out_size = B*128*2 floats).
// ---------------------------------------------------------------------------
template<int MODE>
__global__ __launch_bounds__(256) void final_out(
    const float2* __restrict__ v, const float* __restrict__ Wout,
    const float* __restrict__ bout, float* __restrict__ out)
{
  __shared__ float2 vt[64][64];
  const int t = threadIdx.x;
  const size_t b0 = (size_t)blockIdx.x * 64;
  for (int it = 0; it < 16; ++it) {
    int idx = it * 256 + t;
    int r = idx >> 6, w = idx & 63;
    vt[r][w] = v[(b0 + r) * 64 + w];
  }
  __syncthreads();
  const int f = t & 127, rg = t >> 7;   // 32 rows per thread
  float2 acc[32] = {};
  for (int j = 0; j < 64; ++j) {
    float wv = Wout[f * 64 + j];
    #pragma unroll
    for (int r = 0; r < 32; ++r) {
      float2 vv = vt[rg * 32 + r][j];   // broadcast
      acc[r].x += vv.x * wv;
      acc[r].y += vv.y * wv;
    }
  }
  float bb = bout[f];
  #pragma unroll
  for (int r = 0; r < 32; ++r) {
    size_t idx = (b0 + rg * 32 + r) * 128 + f;
    if (MODE == 0) {
      out[idx] = acc[r].x + bb;
    } else {
      ((float2*)out)[idx] = make_float2(acc[r].x + bb, acc[r].y);
    }
  }
}

// ---------------------------------------------------------------------------
extern "C" void kernel_launch(void* const* d_in, const int* in_sizes, int n_in,
                              void* d_out, int out_size, void* d_ws, size_t ws_size,
                              hipStream_t stream)
{
  (void)in_sizes; (void)n_in; (void)ws_size;
  const float* geom = (const float*)d_in[0];
  const float* Win  = (const float*)d_in[1];
  const float* bin  = (const float*)d_in[2];
  const float* Wh1  = (const float*)d_in[3];
  const float* bh1  = (const float*)d_in[4];
  const float* Wh2  = (const float*)d_in[5];
  const float* bh2  = (const float*)d_in[6];
  const float* w0   = (const float*)d_in[7];
  const float* w1   = (const float*)d_in[8];
  const float* l1W  = (const float*)d_in[9];
  const float* l1b  = (const float*)d_in[10];
  const float* l2W  = (const float*)d_in[11];
  const float* l2b  = (const float*)d_in[12];
  const float* Wout = (const float*)d_in[13];
  const float* bout = (const float*)d_in[14];

  char* ws = (char*)d_ws;
  const size_t MB = 1048576ull;
  // Peak workspace = 128 MB:
  //   [0,64MB)    x2 [32768,512] f32 (full)
  //   [64,128MB)  x1-half [16384,1024] f32 during MLP chunks;
  //               afterwards reused: x3 @64MB (8MB), S0 @72MB (16MB),
  //               S1 @88MB (16MB), consts @104MB (~34KB).
  float*  x2  = (float*)(ws);
  float*  x1h = (float*)(ws + 64 * MB);
  float*  x3  = (float*)(ws + 64 * MB);
  float2* S0  = (float2*)(ws + 72 * MB);
  float2* S1  = (float2*)(ws + 88 * MB);
  float2* Ap  = (float2*)(ws + 104 * MB);
  float2* Am  = (float2*)(ws + 104 * MB + 512);
  float2* b2c = (float2*)(ws + 104 * MB + 1024);
  float2* Q   = (float2*)(ws + 104 * MB + 1536);

  // MLP encoder, chunked over 2 batch halves (M_half = 16384 = 128*128)
  for (int c = 0; c < 2; ++c) {
    const float* gchunk = geom + (size_t)c * 16384 * 512;
    float* x2chunk = x2 + (size_t)c * 16384 * 512;
    gemm_bf16<128,128,64,64><<<dim3(128, 8), 256, 0, stream>>>(gchunk, Win, bin, x1h, 16384, 1024, 512);
    gemm_bf16<128,128,64,64><<<dim3(128, 4), 256, 0, stream>>>(x1h, Wh1, bh1, x2chunk, 16384, 512, 1024);
  }
  gemm_bf16<128, 64,64,32><<<dim3(256, 1), 256, 0, stream>>>(x2, Wh2, bh2, x3, 32768, 64, 512);
  // constants (A+/-, Q = M@lin2_W, b2c = M@lin2_b) — parallel, 17 blocks
  precompute<<<17, 256, 0, stream>>>(w0, w1, l2W, l2b, Ap, Am, Q, b2c);
  // fftn: 64-pt along axis1, then 32768-pt along axis0 (two-stage)
  dft64_rows<<<512, 256, 0, stream>>>(x3, S0);
  fft_stage1<-1><<<512, 256, 0, stream>>>(S0, S1);
  fft_stage2<-1, false><<<512, 256, 0, stream>>>(S1, S0);
  // mode collapse + lin1 + crelu + (ifft64-folded lin2)
  pw_lin<<<1024, 256, 0, stream>>>(S0, Ap, Am, l1W, l1b, Q, b2c, S1);
  // inverse 32768-pt along axis0 (with 1/32768)
  fft_stage1<1><<<512, 256, 0, stream>>>(S1, S0);
  fft_stage2<1, true><<<512, 256, 0, stream>>>(S0, S1);
  // W_out + b_out -> output (layout per out_size; see header comment)
  if (out_size >= 8388608) {
    final_out<1><<<512, 256, 0, stream>>>(S1, Wout, bout, (float*)d_out);
  } else {
    final_out<0><<<512, 256, 0, stream>>>(S1, Wout, bout, (float*)d_out);
  }
}

// Round 6
// 667.821 us; speedup vs baseline: 1.7784x; 1.5042x over previous
//
#include <hip/hip_runtime.h>
#include <hip/hip_bf16.h>

// ---------------------------------------------------------------------------
// FieldPredictionNetwork. R6: all-bf16 MLP pipeline.
//  - geom + MLP weights pre-converted to bf16 (once, elementwise kernels)
//  - GEMMs: bf16 in / bf16 activations out, BK=64, async global_load_lds
//    (16B) staging with XOR swizzle (col^=row&7) -> conflict-free ds_read_b128
//  - FFT / pointwise chain unchanged from R5 (fp32, two-stage 128x256 DFT)
// Peak workspace 98 MB.
// ---------------------------------------------------------------------------

#define PI2F 6.28318530717958647692f

typedef __attribute__((ext_vector_type(8))) short short8;
typedef __attribute__((ext_vector_type(4))) float f32x4;

__device__ __forceinline__ unsigned short f2bf(float f) {
  unsigned int u = __float_as_uint(f);
  u += 0x7fff + ((u >> 16) & 1);          // RN-even
  return (unsigned short)(u >> 16);
}
__device__ __forceinline__ unsigned int pack_bf16x2(float a, float b) {
  return (unsigned int)f2bf(a) | ((unsigned int)f2bf(b) << 16);
}

// async 16B global->LDS DMA; lds dest must be wave-uniform (HW adds lane*16)
__device__ __forceinline__ void gl2lds16(const void* gptr, const void* lptr) {
  __builtin_amdgcn_global_load_lds(
      (const __attribute__((address_space(1))) unsigned int*)(unsigned long long)gptr,
      (__attribute__((address_space(3))) unsigned int*)(unsigned int)(unsigned long long)lptr,
      16, 0, 0);
}

// ---------------------------------------------------------------------------
// f32 -> bf16 pack (4 elems/thread)
// ---------------------------------------------------------------------------
__global__ __launch_bounds__(256) void f32_to_bf16_k(
    const float* __restrict__ src, unsigned short* __restrict__ dst, int n4)
{
  int i = blockIdx.x * 256 + threadIdx.x;
  if (i < n4) {
    float4 v = ((const float4*)src)[i];
    uint2 p;
    p.x = pack_bf16x2(v.x, v.y);
    p.y = pack_bf16x2(v.z, v.w);
    ((uint2*)dst)[i] = p;
  }
}

// ---------------------------------------------------------------------------
// GEMM: C = relu(A @ Bw^T + bias). A [M,K] bf16, Bw [N,K] bf16, bias f32.
// OUT = ushort (bf16) or float. BK=64, 4 waves, async LDS staging + swizzle.
// LDS layout: row-major [row][8 x 16B-chunks], chunk col' = col ^ (row&7).
// ---------------------------------------------------------------------------
template<int BM, int BN, int WM, int WN, typename OUT>
__global__ __launch_bounds__(256) void gemm_async(
    const unsigned short* __restrict__ A, const unsigned short* __restrict__ Bw,
    const float* __restrict__ bias, OUT* __restrict__ C,
    int M, int N, int K)
{
  constexpr int BK = 64;
  __shared__ __align__(16) unsigned short lA[BM * BK];
  __shared__ __align__(16) unsigned short lB[BN * BK];
  const int tid = threadIdx.x;
  const int lane = tid & 63;
  const int wv = tid >> 6;
  const int q = lane >> 4, lr = lane & 15;
  const int x7 = lr & 7;
  constexpr int WN_CNT = BN / WN;
  const int wm = (wv / WN_CNT) * WM;
  const int wn = (wv % WN_CNT) * WN;
  const size_t m0 = (size_t)blockIdx.x * BM;
  const size_t n0 = (size_t)blockIdx.y * BN;
  constexpr int MI = WM / 16, NI = WN / 16;
  f32x4 acc[MI][NI] = {};
  constexpr int A_INSTR = BM * BK / 512;   // 1024B DMA instructions
  constexpr int B_INSTR = BN * BK / 512;
  constexpr int A_PW = A_INSTR / 4, B_PW = B_INSTR / 4;
  (void)M;

  for (int k0 = 0; k0 < K; k0 += BK) {
    __syncthreads();                        // all waves done reading prev tile
    #pragma unroll
    for (int s = 0; s < A_PW; ++s) {
      int instr = wv * A_PW + s;
      int pc = instr * 64 + lane;           // physical 16B chunk
      int row = pc >> 3, col = pc & 7;
      int lc = col ^ (row & 7);             // logical chunk fetched here
      gl2lds16(A + (m0 + row) * K + k0 + lc * 8, lA + instr * 512);
    }
    #pragma unroll
    for (int s = 0; s < B_PW; ++s) {
      int instr = wv * B_PW + s;
      int pc = instr * 64 + lane;
      int row = pc >> 3, col = pc & 7;
      int lc = col ^ (row & 7);
      gl2lds16(Bw + (n0 + row) * K + k0 + lc * 8, lB + instr * 512);
    }
    __syncthreads();                        // drains vmcnt -> LDS visible
    #pragma unroll
    for (int t = 0; t < 2; ++t) {
      short8 af[MI], bfr[NI];
      #pragma unroll
      for (int i = 0; i < MI; ++i) {
        int r = wm + i * 16 + lr;
        af[i] = *(const short8*)(lA + r * 64 + (((t << 2) | q) ^ x7) * 8);
      }
      #pragma unroll
      for (int j = 0; j < NI; ++j) {
        int r = wn + j * 16 + lr;
        bfr[j] = *(const short8*)(lB + r * 64 + (((t << 2) | q) ^ x7) * 8);
      }
      #pragma unroll
      for (int i = 0; i < MI; ++i)
        #pragma unroll
        for (int j = 0; j < NI; ++j)
          acc[i][j] = __builtin_amdgcn_mfma_f32_16x16x32_bf16(af[i], bfr[j], acc[i][j], 0, 0, 0);
    }
  }
  // epilogue: D col = lane&15, row = quad*4 + reg
  #pragma unroll
  for (int i = 0; i < MI; ++i)
    #pragma unroll
    for (int j = 0; j < NI; ++j) {
      size_t col = n0 + wn + j * 16 + lr;
      float bv = bias[col];
      #pragma unroll
      for (int r = 0; r < 4; ++r) {
        size_t row = m0 + wm + i * 16 + q * 4 + r;
        float v = acc[i][j][r] + bv;
        v = v > 0.f ? v : 0.f;
        if (sizeof(OUT) == 2) ((unsigned short*)C)[row * N + col] = f2bf(v);
        else                  ((float*)C)[row * N + col] = v;
      }
    }
}

// ---------------------------------------------------------------------------
// Precompute (parallel): block 0 -> Ap/Am/b2c; blocks 1..16 -> Q.
// ---------------------------------------------------------------------------
__global__ __launch_bounds__(256) void precompute(
    const float* __restrict__ w0, const float* __restrict__ w1,
    const float* __restrict__ l2W, const float* __restrict__ l2b,
    float2* __restrict__ Ap, float2* __restrict__ Am,
    float2* __restrict__ Q, float2* __restrict__ b2c)
{
  const int t = threadIdx.x;
  const int blk = blockIdx.x;
  if (blk == 0) {
    if (t < 64) {
      float apx = 0, apy = 0, amx = 0, amy = 0;
      for (int m = 0; m < 32; ++m) {
        float s0 = w0[m * 64 + t];
        float cf = w1[m * 64 + t] * s0;
        float sn, cs; sincosf(PI2F * (float)m / 32.f, &sn, &cs);
        if (s0 > 0.f)      { apx += cs * cf; apy += sn * cf; }
        else if (s0 < 0.f) { amx += cs * cf; amy += sn * cf; }
      }
      Ap[t] = make_float2(apx, apy);
      Am[t] = make_float2(amx, amy);
      float bx = 0, by = 0;
      for (int k = 0; k < 64; ++k) {
        float sn, cs; sincosf(PI2F * (float)((t * k) & 63) / 64.f, &sn, &cs);
        float lb = l2b[k] * (1.f / 64.f);
        bx += cs * lb; by += sn * lb;
      }
      b2c[t] = make_float2(bx, by);
    }
  } else {
    int e = (blk - 1) * 256 + t;
    int j = e >> 6, w = e & 63;
    float qx = 0, qy = 0;
    for (int k = 0; k < 64; ++k) {
      float sn, cs; sincosf(PI2F * (float)((j * k) & 63) / 64.f, &sn, &cs);
      float lw = l2W[k * 64 + w] * (1.f / 64.f);
      qx += cs * lw; qy += sn * lw;
    }
    Q[j * 64 + w] = make_float2(qx, qy);
  }
}

// ---------------------------------------------------------------------------
// DFT along axis1 (64-pt forward)
// ---------------------------------------------------------------------------
__global__ __launch_bounds__(256) void dft64_rows(
    const float* __restrict__ x3, float2* __restrict__ xh1)
{
  __shared__ float xt[64][64];
  __shared__ float2 tw[64];
  const int t = threadIdx.x;
  const size_t b0 = (size_t)blockIdx.x * 64;
  for (int it = 0; it < 16; ++it) {
    int idx = it * 256 + t;
    int r = idx >> 6, w = idx & 63;
    xt[r][w] = x3[(b0 + r) * 64 + w];
  }
  if (t < 64) {
    float sn, cs; sincosf(-PI2F * (float)t / 64.f, &sn, &cs);
    tw[t] = make_float2(cs, sn);
  }
  __syncthreads();
  const int k = t & 63, rg = t >> 6;
  float2 acc[16] = {};
  for (int w = 0; w < 64; ++w) {
    float2 tv = tw[(k * w) & 63];
    #pragma unroll
    for (int r = 0; r < 16; ++r) {
      float xv = xt[rg * 16 + r][w];
      acc[r].x += xv * tv.x;
      acc[r].y += xv * tv.y;
    }
  }
  for (int r = 0; r < 16; ++r)
    xh1[(b0 + rg * 16 + r) * 64 + k] = acc[r];
}

// ---------------------------------------------------------------------------
// Batch-axis FFT stage 1 (128-pt over b1) + inter-stage twiddle
// ---------------------------------------------------------------------------
template<int SIGN>
__global__ __launch_bounds__(256) void fft_stage1(
    const float2* __restrict__ X, float2* __restrict__ T)
{
  __shared__ float2 tile[128][32];
  __shared__ float2 tw[128];
  const int blk = blockIdx.x;
  const int b2 = blk >> 1, wh = (blk & 1) * 32;
  const int t = threadIdx.x;
  for (int it = 0; it < 16; ++it) {
    int idx = it * 256 + t;
    int b1 = idx >> 5, wi = idx & 31;
    tile[b1][wi] = X[((size_t)(b1 * 256 + b2)) * 64 + wh + wi];
  }
  if (t < 128) {
    float sn, cs; sincosf(SIGN * PI2F * (float)t / 128.f, &sn, &cs);
    tw[t] = make_float2(cs, sn);
  }
  __syncthreads();
  const int k1g = t >> 3, wg = t & 7;
  float2 acc[4][4] = {};
  for (int b1 = 0; b1 < 128; ++b1) {
    float2 d[4];
    #pragma unroll
    for (int j = 0; j < 4; ++j) d[j] = tile[b1][wg * 4 + j];
    #pragma unroll
    for (int i = 0; i < 4; ++i) {
      float2 tv = tw[((k1g * 4 + i) * b1) & 127];
      #pragma unroll
      for (int j = 0; j < 4; ++j) {
        acc[i][j].x += d[j].x * tv.x - d[j].y * tv.y;
        acc[i][j].y += d[j].x * tv.y + d[j].y * tv.x;
      }
    }
  }
  #pragma unroll
  for (int i = 0; i < 4; ++i) {
    int k1 = k1g * 4 + i;
    float sn, cs;
    sincosf(SIGN * PI2F * (float)(b2 * k1) / 32768.f, &sn, &cs);
    #pragma unroll
    for (int j = 0; j < 4; ++j) {
      float2 a = acc[i][j];
      float2 o = make_float2(a.x * cs - a.y * sn, a.x * sn + a.y * cs);
      T[((size_t)k1 * 256 + b2) * 64 + wh + wg * 4 + j] = o;
    }
  }
}

// ---------------------------------------------------------------------------
// Batch-axis FFT stage 2 (256-pt over b2)
// ---------------------------------------------------------------------------
template<int SIGN, bool SCALE>
__global__ __launch_bounds__(256) void fft_stage2(
    const float2* __restrict__ T, float2* __restrict__ X)
{
  __shared__ float2 tile[256][16];
  __shared__ float2 tw[256];
  const int blk = blockIdx.x;
  const int k1 = blk >> 2, wq = (blk & 3) * 16;
  const int t = threadIdx.x;
  for (int it = 0; it < 16; ++it) {
    int idx = it * 256 + t;
    int r2 = idx >> 4, wi = idx & 15;
    tile[r2][wi] = T[((size_t)k1 * 256 + r2) * 64 + wq + wi];
  }
  {
    float sn, cs; sincosf(SIGN * PI2F * (float)t / 256.f, &sn, &cs);
    tw[t] = make_float2(cs, sn);
  }
  __syncthreads();
  const int k2g = t >> 2, wg = t & 3;
  float2 acc[4][4] = {};
  for (int r2 = 0; r2 < 256; ++r2) {
    float2 d[4];
    #pragma unroll
    for (int j = 0; j < 4; ++j) d[j] = tile[r2][wg * 4 + j];
    #pragma unroll
    for (int i = 0; i < 4; ++i) {
      float2 tv = tw[((k2g * 4 + i) * r2) & 255];
      #pragma unroll
      for (int j = 0; j < 4; ++j) {
        acc[i][j].x += d[j].x * tv.x - d[j].y * tv.y;
        acc[i][j].y += d[j].x * tv.y + d[j].y * tv.x;
      }
    }
  }
  const float sc = SCALE ? (1.f / 32768.f) : 1.f;
  #pragma unroll
  for (int i = 0; i < 4; ++i) {
    size_t row = (size_t)(k1 + 128 * (k2g * 4 + i));
    #pragma unroll
    for (int j = 0; j < 4; ++j) {
      float2 a = acc[i][j];
      X[row * 64 + wq + wg * 4 + j] = make_float2(a.x * sc, a.y * sc);
    }
  }
}

// ---------------------------------------------------------------------------
// Pointwise A+/- fold, lin1 crelu, Q-fold (ifft64+lin2)
// ---------------------------------------------------------------------------
__global__ __launch_bounds__(256) void pw_lin(
    const float2* __restrict__ xh,
    const float2* __restrict__ Ap, const float2* __restrict__ Am,
    const float* __restrict__ l1W, const float* __restrict__ l1b,
    const float2* __restrict__ Q, const float2* __restrict__ b2c,
    float2* __restrict__ u)
{
  __shared__ float2 yt[32][64];
  __shared__ float2 zt[32][64];
  const int t = threadIdx.x;
  const size_t b0 = (size_t)blockIdx.x * 32;
  for (int it = 0; it < 8; ++it) {
    int idx = it * 256 + t;
    int r = idx >> 6, w = idx & 63;
    float2 xv = xh[(b0 + r) * 64 + w];
    float2 Aa = (xv.x >= 0.f) ? Ap[w] : Am[w];
    float2 Ab = (xv.y >= 0.f) ? Ap[w] : Am[w];
    float c1r = xv.x * Aa.x, c1i = xv.x * Aa.y;
    float c2r = xv.y * Ab.x, c2i = xv.y * Ab.y;
    yt[r][w] = make_float2(c1r - c2i, c1i + c2r);
  }
  __syncthreads();
  {
    const int n = t & 63, rg = t >> 6;
    float2 acc[8] = {};
    for (int w = 0; w < 64; ++w) {
      float lw = l1W[n * 64 + w];
      #pragma unroll
      for (int r = 0; r < 8; ++r) {
        float2 yv = yt[rg * 8 + r][w];
        acc[r].x += yv.x * lw;
        acc[r].y += yv.y * lw;
      }
    }
    float bb = l1b[n];
    #pragma unroll
    for (int r = 0; r < 8; ++r) {
      float zr = acc[r].x + bb; zr = zr > 0.f ? zr : 0.f;
      float zi = acc[r].y;      zi = zi > 0.f ? zi : 0.f;
      zt[rg * 8 + r][n] = make_float2(zr, zi);
    }
  }
  __syncthreads();
  {
    const int j = t & 63, rg = t >> 6;
    float2 acc[8] = {};
    for (int w = 0; w < 64; ++w) {
      float2 qv = Q[j * 64 + w];
      #pragma unroll
      for (int r = 0; r < 8; ++r) {
        float2 zv = zt[rg * 8 + r][w];
        acc[r].x += zv.x * qv.x - zv.y * qv.y;
        acc[r].y += zv.x * qv.y + zv.y * qv.x;
      }
    }
    float2 bc = b2c[j];
    #pragma unroll
    for (int r = 0; r < 8; ++r)
      u[(b0 + rg * 8 + r) * 64 + j] = make_float2(acc[r].x + bc.x, acc[r].y + bc.y);
  }
}

// ---------------------------------------------------------------------------
// Final W_out GEMM; MODE 0 = real only, MODE 1 = interleaved (re,im)
// ---------------------------------------------------------------------------
template<int MODE>
__global__ __launch_bounds__(256) void final_out(
    const float2* __restrict__ v, const float* __restrict__ Wout,
    const float* __restrict__ bout, float* __restrict__ out)
{
  __shared__ float2 vt[64][64];
  const int t = threadIdx.x;
  const size_t b0 = (size_t)blockIdx.x * 64;
  for (int it = 0; it < 16; ++it) {
    int idx = it * 256 + t;
    int r = idx >> 6, w = idx & 63;
    vt[r][w] = v[(b0 + r) * 64 + w];
  }
  __syncthreads();
  const int f = t & 127, rg = t >> 7;
  float2 acc[32] = {};
  for (int j = 0; j < 64; ++j) {
    float wv = Wout[f * 64 + j];
    #pragma unroll
    for (int r = 0; r < 32; ++r) {
      float2 vv = vt[rg * 32 + r][j];
      acc[r].x += vv.x * wv;
      acc[r].y += vv.y * wv;
    }
  }
  float bb = bout[f];
  #pragma unroll
  for (int r = 0; r < 32; ++r) {
    size_t idx = (b0 + rg * 32 + r) * 128 + f;
    if (MODE == 0) out[idx] = acc[r].x + bb;
    else ((float2*)out)[idx] = make_float2(acc[r].x + bb, acc[r].y);
  }
}

// ---------------------------------------------------------------------------
extern "C" void kernel_launch(void* const* d_in, const int* in_sizes, int n_in,
                              void* d_out, int out_size, void* d_ws, size_t ws_size,
                              hipStream_t stream)
{
  (void)in_sizes; (void)n_in; (void)ws_size;
  const float* geom = (const float*)d_in[0];
  const float* Win  = (const float*)d_in[1];
  const float* bin  = (const float*)d_in[2];
  const float* Wh1  = (const float*)d_in[3];
  const float* bh1  = (const float*)d_in[4];
  const float* Wh2  = (const float*)d_in[5];
  const float* bh2  = (const float*)d_in[6];
  const float* w0   = (const float*)d_in[7];
  const float* w1   = (const float*)d_in[8];
  const float* l1W  = (const float*)d_in[9];
  const float* l1b  = (const float*)d_in[10];
  const float* l2W  = (const float*)d_in[11];
  const float* l2b  = (const float*)d_in[12];
  const float* Wout = (const float*)d_in[13];
  const float* bout = (const float*)d_in[14];

  char* ws = (char*)d_ws;
  const size_t MB = 1048576ull;
  // Workspace (peak 98.1 MB):
  //   [0,32)   geomb (bf16) during gemm1; x2b (bf16 32MB) after
  //   [32,96)  x1b (bf16 64MB) during gemm1/2; then x3 f32 @32 (8MB),
  //            S0 @40 (16MB), S1 @56 (16MB), consts @72
  //   [96,99)  bf16 weights (Winb 1MB, Wh1b 1MB, Wh2b 64KB)
  unsigned short* geomb = (unsigned short*)(ws);
  unsigned short* x2b   = (unsigned short*)(ws);
  unsigned short* x1b   = (unsigned short*)(ws + 32 * MB);
  float*  x3  = (float*)(ws + 32 * MB);
  float2* S0  = (float2*)(ws + 40 * MB);
  float2* S1  = (float2*)(ws + 56 * MB);
  float2* Ap  = (float2*)(ws + 72 * MB);
  float2* Am  = (float2*)(ws + 72 * MB + 512);
  float2* b2c = (float2*)(ws + 72 * MB + 1024);
  float2* Q   = (float2*)(ws + 72 * MB + 1536);
  unsigned short* Winb = (unsigned short*)(ws + 96 * MB);
  unsigned short* Wh1b = (unsigned short*)(ws + 97 * MB);
  unsigned short* Wh2b = (unsigned short*)(ws + 98 * MB);

  // bf16 conversions (geom 16.7M elems; weights small)
  f32_to_bf16_k<<<16384, 256, 0, stream>>>(geom, geomb, 4194304);
  f32_to_bf16_k<<<512, 256, 0, stream>>>(Win, Winb, 131072);
  f32_to_bf16_k<<<512, 256, 0, stream>>>(Wh1, Wh1b, 131072);
  f32_to_bf16_k<<<32, 256, 0, stream>>>(Wh2, Wh2b, 8192);

  // MLP encoder (full batch)
  gemm_async<128,128,64,64,unsigned short><<<dim3(256, 8), 256, 0, stream>>>(
      geomb, Winb, bin, x1b, 32768, 1024, 512);
  gemm_async<128,128,64,64,unsigned short><<<dim3(256, 4), 256, 0, stream>>>(
      x1b, Wh1b, bh1, x2b, 32768, 512, 1024);
  gemm_async<128, 64,64,32,float><<<dim3(256, 1), 256, 0, stream>>>(
      x2b, Wh2b, bh2, x3, 32768, 64, 512);

  precompute<<<17, 256, 0, stream>>>(w0, w1, l2W, l2b, Ap, Am, Q, b2c);
  // fftn: 64-pt along axis1, then 32768-pt along axis0 (two-stage)
  dft64_rows<<<512, 256, 0, stream>>>(x3, S0);
  fft_stage1<-1><<<512, 256, 0, stream>>>(S0, S1);
  fft_stage2<-1, false><<<512, 256, 0, stream>>>(S1, S0);
  pw_lin<<<1024, 256, 0, stream>>>(S0, Ap, Am, l1W, l1b, Q, b2c, S1);
  fft_stage1<1><<<512, 256, 0, stream>>>(S1, S0);
  fft_stage2<1, true><<<512, 256, 0, stream>>>(S0, S1);
  if (out_size >= 8388608) {
    final_out<1><<<512, 256, 0, stream>>>(S1, Wout, bout, (float*)d_out);
  } else {
    final_out<0><<<512, 256, 0, stream>>>(S1, Wout, bout, (float*)d_out);
  }
}

// Round 7
// 555.957 us; speedup vs baseline: 2.1362x; 1.2012x over previous
//
#include <hip/hip_runtime.h>
#include <hip/hip_bf16.h>

// ---------------------------------------------------------------------------
// FieldPredictionNetwork. R7: radix-decomposed batch-axis FFT stages.
//  - fft_stage2: 256-pt DFT = radix-16 x radix-16 (7.8x fewer FMAs), in-place
//    LDS reuse across a barrier, pad-17 stride.
//  - fft_stage1: 128-pt DFT = radix-16 x radix-8 (5x fewer FMAs), inter-stage
//    W_32768 twiddle via incremental rotation, pad-33 stride.
//  - GEMMs (bf16 async global_load_lds), dft64, pw_lin, final_out unchanged.
// ---------------------------------------------------------------------------

#define PI2F 6.28318530717958647692f

typedef __attribute__((ext_vector_type(8))) short short8;
typedef __attribute__((ext_vector_type(4))) float f32x4;

__device__ __forceinline__ unsigned short f2bf(float f) {
  unsigned int u = __float_as_uint(f);
  u += 0x7fff + ((u >> 16) & 1);          // RN-even
  return (unsigned short)(u >> 16);
}
__device__ __forceinline__ unsigned int pack_bf16x2(float a, float b) {
  return (unsigned int)f2bf(a) | ((unsigned int)f2bf(b) << 16);
}

// async 16B global->LDS DMA; lds dest must be wave-uniform (HW adds lane*16)
__device__ __forceinline__ void gl2lds16(const void* gptr, const void* lptr) {
  __builtin_amdgcn_global_load_lds(
      (const __attribute__((address_space(1))) unsigned int*)(unsigned long long)gptr,
      (__attribute__((address_space(3))) unsigned int*)(unsigned int)(unsigned long long)lptr,
      16, 0, 0);
}

// ---------------------------------------------------------------------------
// f32 -> bf16 pack (4 elems/thread)
// ---------------------------------------------------------------------------
__global__ __launch_bounds__(256) void f32_to_bf16_k(
    const float* __restrict__ src, unsigned short* __restrict__ dst, int n4)
{
  int i = blockIdx.x * 256 + threadIdx.x;
  if (i < n4) {
    float4 v = ((const float4*)src)[i];
    uint2 p;
    p.x = pack_bf16x2(v.x, v.y);
    p.y = pack_bf16x2(v.z, v.w);
    ((uint2*)dst)[i] = p;
  }
}

// ---------------------------------------------------------------------------
// GEMM: C = relu(A @ Bw^T + bias). A [M,K] bf16, Bw [N,K] bf16, bias f32.
// OUT = ushort (bf16) or float. BK=64, 4 waves, async LDS staging + swizzle.
// ---------------------------------------------------------------------------
template<int BM, int BN, int WM, int WN, typename OUT>
__global__ __launch_bounds__(256) void gemm_async(
    const unsigned short* __restrict__ A, const unsigned short* __restrict__ Bw,
    const float* __restrict__ bias, OUT* __restrict__ C,
    int M, int N, int K)
{
  constexpr int BK = 64;
  __shared__ __align__(16) unsigned short lA[BM * BK];
  __shared__ __align__(16) unsigned short lB[BN * BK];
  const int tid = threadIdx.x;
  const int lane = tid & 63;
  const int wv = tid >> 6;
  const int q = lane >> 4, lr = lane & 15;
  const int x7 = lr & 7;
  constexpr int WN_CNT = BN / WN;
  const int wm = (wv / WN_CNT) * WM;
  const int wn = (wv % WN_CNT) * WN;
  const size_t m0 = (size_t)blockIdx.x * BM;
  const size_t n0 = (size_t)blockIdx.y * BN;
  constexpr int MI = WM / 16, NI = WN / 16;
  f32x4 acc[MI][NI] = {};
  constexpr int A_INSTR = BM * BK / 512;   // 1024B DMA instructions
  constexpr int B_INSTR = BN * BK / 512;
  constexpr int A_PW = A_INSTR / 4, B_PW = B_INSTR / 4;
  (void)M;

  for (int k0 = 0; k0 < K; k0 += BK) {
    __syncthreads();
    #pragma unroll
    for (int s = 0; s < A_PW; ++s) {
      int instr = wv * A_PW + s;
      int pc = instr * 64 + lane;
      int row = pc >> 3, col = pc & 7;
      int lc = col ^ (row & 7);
      gl2lds16(A + (m0 + row) * K + k0 + lc * 8, lA + instr * 512);
    }
    #pragma unroll
    for (int s = 0; s < B_PW; ++s) {
      int instr = wv * B_PW + s;
      int pc = instr * 64 + lane;
      int row = pc >> 3, col = pc & 7;
      int lc = col ^ (row & 7);
      gl2lds16(Bw + (n0 + row) * K + k0 + lc * 8, lB + instr * 512);
    }
    __syncthreads();
    #pragma unroll
    for (int t = 0; t < 2; ++t) {
      short8 af[MI], bfr[NI];
      #pragma unroll
      for (int i = 0; i < MI; ++i) {
        int r = wm + i * 16 + lr;
        af[i] = *(const short8*)(lA + r * 64 + (((t << 2) | q) ^ x7) * 8);
      }
      #pragma unroll
      for (int j = 0; j < NI; ++j) {
        int r = wn + j * 16 + lr;
        bfr[j] = *(const short8*)(lB + r * 64 + (((t << 2) | q) ^ x7) * 8);
      }
      #pragma unroll
      for (int i = 0; i < MI; ++i)
        #pragma unroll
        for (int j = 0; j < NI; ++j)
          acc[i][j] = __builtin_amdgcn_mfma_f32_16x16x32_bf16(af[i], bfr[j], acc[i][j], 0, 0, 0);
    }
  }
  #pragma unroll
  for (int i = 0; i < MI; ++i)
    #pragma unroll
    for (int j = 0; j < NI; ++j) {
      size_t col = n0 + wn + j * 16 + lr;
      float bv = bias[col];
      #pragma unroll
      for (int r = 0; r < 4; ++r) {
        size_t row = m0 + wm + i * 16 + q * 4 + r;
        float v = acc[i][j][r] + bv;
        v = v > 0.f ? v : 0.f;
        if (sizeof(OUT) == 2) ((unsigned short*)C)[row * N + col] = f2bf(v);
        else                  ((float*)C)[row * N + col] = v;
      }
    }
}

// ---------------------------------------------------------------------------
// Precompute (parallel): block 0 -> Ap/Am/b2c; blocks 1..16 -> Q.
// ---------------------------------------------------------------------------
__global__ __launch_bounds__(256) void precompute(
    const float* __restrict__ w0, const float* __restrict__ w1,
    const float* __restrict__ l2W, const float* __restrict__ l2b,
    float2* __restrict__ Ap, float2* __restrict__ Am,
    float2* __restrict__ Q, float2* __restrict__ b2c)
{
  const int t = threadIdx.x;
  const int blk = blockIdx.x;
  if (blk == 0) {
    if (t < 64) {
      float apx = 0, apy = 0, amx = 0, amy = 0;
      for (int m = 0; m < 32; ++m) {
        float s0 = w0[m * 64 + t];
        float cf = w1[m * 64 + t] * s0;
        float sn, cs; sincosf(PI2F * (float)m / 32.f, &sn, &cs);
        if (s0 > 0.f)      { apx += cs * cf; apy += sn * cf; }
        else if (s0 < 0.f) { amx += cs * cf; amy += sn * cf; }
      }
      Ap[t] = make_float2(apx, apy);
      Am[t] = make_float2(amx, amy);
      float bx = 0, by = 0;
      for (int k = 0; k < 64; ++k) {
        float sn, cs; sincosf(PI2F * (float)((t * k) & 63) / 64.f, &sn, &cs);
        float lb = l2b[k] * (1.f / 64.f);
        bx += cs * lb; by += sn * lb;
      }
      b2c[t] = make_float2(bx, by);
    }
  } else {
    int e = (blk - 1) * 256 + t;
    int j = e >> 6, w = e & 63;
    float qx = 0, qy = 0;
    for (int k = 0; k < 64; ++k) {
      float sn, cs; sincosf(PI2F * (float)((j * k) & 63) / 64.f, &sn, &cs);
      float lw = l2W[k * 64 + w] * (1.f / 64.f);
      qx += cs * lw; qy += sn * lw;
    }
    Q[j * 64 + w] = make_float2(qx, qy);
  }
}

// ---------------------------------------------------------------------------
// DFT along axis1 (64-pt forward)
// ---------------------------------------------------------------------------
__global__ __launch_bounds__(256) void dft64_rows(
    const float* __restrict__ x3, float2* __restrict__ xh1)
{
  __shared__ float xt[64][64];
  __shared__ float2 tw[64];
  const int t = threadIdx.x;
  const size_t b0 = (size_t)blockIdx.x * 64;
  for (int it = 0; it < 16; ++it) {
    int idx = it * 256 + t;
    int r = idx >> 6, w = idx & 63;
    xt[r][w] = x3[(b0 + r) * 64 + w];
  }
  if (t < 64) {
    float sn, cs; sincosf(-PI2F * (float)t / 64.f, &sn, &cs);
    tw[t] = make_float2(cs, sn);
  }
  __syncthreads();
  const int k = t & 63, rg = t >> 6;
  float2 acc[16] = {};
  for (int w = 0; w < 64; ++w) {
    float2 tv = tw[(k * w) & 63];
    #pragma unroll
    for (int r = 0; r < 16; ++r) {
      float xv = xt[rg * 16 + r][w];
      acc[r].x += xv * tv.x;
      acc[r].y += xv * tv.y;
    }
  }
  for (int r = 0; r < 16; ++r)
    xh1[(b0 + rg * 16 + r) * 64 + k] = acc[r];
}

// ---------------------------------------------------------------------------
// Batch-axis FFT stage 1: 128-pt DFT over b1 as radix-16 x radix-8, then
// inter-stage twiddle W32768^{b2*k1} (incremental rotation).
// Block: (b2, w-half of 32). tile[b1][w] pad-33, reused in place for y.
//   b1 = 8*n1 + n2 (n1<16, n2<8); k1 = k1p + 16*k2p (k1p<16, k2p<8)
//   y[n2][k1p] = W128^{n2 k1p} * sum_n1 x[8n1+n2] W16^{n1 k1p}
//   X[k1]      = sum_n2 y[n2][k1p] W8^{n2 k2p}
// ---------------------------------------------------------------------------
template<int SIGN>
__global__ __launch_bounds__(256) void fft_stage1(
    const float2* __restrict__ Xin, float2* __restrict__ T)
{
  __shared__ float2 tile[128 * 33];
  __shared__ float2 tw16s[16];
  const int blk = blockIdx.x;
  const int b2 = blk >> 1, wh = (blk & 1) * 32;
  const int t = threadIdx.x;
  for (int it = 0; it < 16; ++it) {
    int idx = it * 256 + t;
    int b1 = idx >> 5, wi = idx & 31;
    tile[b1 * 33 + wi] = Xin[((size_t)(b1 * 256 + b2)) * 64 + wh + wi];
  }
  if (t < 16) {
    float sn, cs; sincosf(SIGN * PI2F * (float)t / 16.f, &sn, &cs);
    tw16s[t] = make_float2(cs, sn);
  }
  __syncthreads();
  // ---- phase A: thread -> pair p=t>>1 (n2=p>>4, k1p=p&15), w0=(t&1)*16
  const int p = t >> 1, n2a = p >> 4, k1pa = p & 15, w0 = (t & 1) * 16;
  float2 tw16[16];
  #pragma unroll
  for (int j = 0; j < 16; ++j) tw16[j] = tw16s[j];
  float2 ya[16] = {};
  #pragma unroll
  for (int n1 = 0; n1 < 16; ++n1) {
    float2 tv = tw16[(n1 * k1pa) & 15];
    const float2* row = &tile[(8 * n1 + n2a) * 33 + w0];
    #pragma unroll
    for (int w = 0; w < 16; ++w) {
      float2 d = row[w];
      ya[w].x += d.x * tv.x - d.y * tv.y;
      ya[w].y += d.x * tv.y + d.y * tv.x;
    }
  }
  {
    float sn, cs; sincosf(SIGN * PI2F * (float)(n2a * k1pa) / 128.f, &sn, &cs);
    #pragma unroll
    for (int w = 0; w < 16; ++w) {
      float2 a = ya[w];
      ya[w] = make_float2(a.x * cs - a.y * sn, a.x * sn + a.y * cs);
    }
  }
  __syncthreads();                       // all phase-A reads of tile done
  {
    float2* yrow = &tile[(n2a * 16 + k1pa) * 33 + w0];
    #pragma unroll
    for (int w = 0; w < 16; ++w) yrow[w] = ya[w];
  }
  __syncthreads();                       // y visible
  // ---- phase B: thread -> (w = t&31, q = t>>5); k1p in {q, q+8}
  const int wB = t & 31, qB = t >> 5;
  float2 w8[8];
  #pragma unroll
  for (int j = 0; j < 8; ++j) w8[j] = tw16[2 * j];   // W8^j = W16^{2j}
  float sstep, cstep;
  sincosf(SIGN * PI2F * (float)(16 * b2) / 32768.f, &sstep, &cstep);
  #pragma unroll
  for (int h = 0; h < 2; ++h) {
    const int k1p = qB + 8 * h;
    float2 acc[8] = {};
    #pragma unroll
    for (int n2 = 0; n2 < 8; ++n2) {
      float2 d = tile[(n2 * 16 + k1p) * 33 + wB];
      #pragma unroll
      for (int k2p = 0; k2p < 8; ++k2p) {
        float2 tv = w8[(n2 * k2p) & 7];
        acc[k2p].x += d.x * tv.x - d.y * tv.y;
        acc[k2p].y += d.x * tv.y + d.y * tv.x;
      }
    }
    float sb, cb;
    sincosf(SIGN * PI2F * (float)(b2 * k1p) / 32768.f, &sb, &cb);
    float2 rot = make_float2(cb, sb);
    #pragma unroll
    for (int k2p = 0; k2p < 8; ++k2p) {
      int k1 = k1p + 16 * k2p;
      float2 a = acc[k2p];
      float2 o = make_float2(a.x * rot.x - a.y * rot.y,
                             a.x * rot.y + a.y * rot.x);
      T[((size_t)k1 * 256 + b2) * 64 + wh + wB] = o;
      float nrx = rot.x * cstep - rot.y * sstep;
      rot.y = rot.x * sstep + rot.y * cstep;
      rot.x = nrx;
    }
  }
}

// ---------------------------------------------------------------------------
// Batch-axis FFT stage 2: 256-pt DFT over b2 as radix-16 x radix-16.
// Block: (k1 of 128, w-quarter of 16). tile[b2][w] pad-17, in-place y reuse.
//   b2 = 16*n1 + n2; k2 = k1p + 16*k2p
//   y[n2][k1p] = W256^{n2 k1p} * sum_n1 x[16n1+n2] W16^{n1 k1p}
//   X[k2]      = sum_n2 y[n2][k1p] W16^{n2 k2p};  out row = k1 + 128*k2
// ---------------------------------------------------------------------------
template<int SIGN, bool SCALE>
__global__ __launch_bounds__(256) void fft_stage2(
    const float2* __restrict__ T, float2* __restrict__ X)
{
  __shared__ float2 tile[256 * 17];
  __shared__ float2 tw16s[16];
  const int blk = blockIdx.x;
  const int k1 = blk >> 2, wq = (blk & 3) * 16;
  const int t = threadIdx.x;
  for (int it = 0; it < 16; ++it) {
    int idx = it * 256 + t;
    int r2 = idx >> 4, wi = idx & 15;
    tile[r2 * 17 + wi] = T[((size_t)k1 * 256 + r2) * 64 + wq + wi];
  }
  if (t < 16) {
    float sn, cs; sincosf(SIGN * PI2F * (float)t / 16.f, &sn, &cs);
    tw16s[t] = make_float2(cs, sn);
  }
  __syncthreads();
  // ---- phase A: thread -> (n2 = t>>4, k1p = t&15)
  const int n2a = t >> 4, k1pa = t & 15;
  float2 tw16[16];
  #pragma unroll
  for (int j = 0; j < 16; ++j) tw16[j] = tw16s[j];
  float2 ya[16] = {};
  #pragma unroll
  for (int n1 = 0; n1 < 16; ++n1) {
    float2 tv = tw16[(n1 * k1pa) & 15];
    const float2* row = &tile[(16 * n1 + n2a) * 17];
    #pragma unroll
    for (int w = 0; w < 16; ++w) {
      float2 d = row[w];
      ya[w].x += d.x * tv.x - d.y * tv.y;
      ya[w].y += d.x * tv.y + d.y * tv.x;
    }
  }
  {
    float sn, cs; sincosf(SIGN * PI2F * (float)(n2a * k1pa) / 256.f, &sn, &cs);
    #pragma unroll
    for (int w = 0; w < 16; ++w) {
      float2 a = ya[w];
      ya[w] = make_float2(a.x * cs - a.y * sn, a.x * sn + a.y * cs);
    }
  }
  __syncthreads();                       // all phase-A reads done
  {
    float2* yrow = &tile[(n2a * 16 + k1pa) * 17];
    #pragma unroll
    for (int w = 0; w < 16; ++w) yrow[w] = ya[w];
  }
  __syncthreads();                       // y visible
  // ---- phase B: thread -> (k1p = t>>4, w = t&15)
  const int k1pb = t >> 4, wB = t & 15;
  float2 acc[16] = {};
  #pragma unroll
  for (int n2 = 0; n2 < 16; ++n2) {
    float2 d = tile[(n2 * 16 + k1pb) * 17 + wB];
    #pragma unroll
    for (int k2p = 0; k2p < 16; ++k2p) {
      float2 tv = tw16[(n2 * k2p) & 15];
      acc[k2p].x += d.x * tv.x - d.y * tv.y;
      acc[k2p].y += d.x * tv.y + d.y * tv.x;
    }
  }
  const float sc = SCALE ? (1.f / 32768.f) : 1.f;
  #pragma unroll
  for (int k2p = 0; k2p < 16; ++k2p) {
    int k2 = k1pb + 16 * k2p;
    size_t row = (size_t)(k1 + 128 * k2);
    X[row * 64 + wq + wB] = make_float2(acc[k2p].x * sc, acc[k2p].y * sc);
  }
}

// ---------------------------------------------------------------------------
// Pointwise A+/- fold, lin1 crelu, Q-fold (ifft64+lin2)
// ---------------------------------------------------------------------------
__global__ __launch_bounds__(256) void pw_lin(
    const float2* __restrict__ xh,
    const float2* __restrict__ Ap, const float2* __restrict__ Am,
    const float* __restrict__ l1W, const float* __restrict__ l1b,
    const float2* __restrict__ Q, const float2* __restrict__ b2c,
    float2* __restrict__ u)
{
  __shared__ float2 yt[32][64];
  __shared__ float2 zt[32][64];
  const int t = threadIdx.x;
  const size_t b0 = (size_t)blockIdx.x * 32;
  for (int it = 0; it < 8; ++it) {
    int idx = it * 256 + t;
    int r = idx >> 6, w = idx & 63;
    float2 xv = xh[(b0 + r) * 64 + w];
    float2 Aa = (xv.x >= 0.f) ? Ap[w] : Am[w];
    float2 Ab = (xv.y >= 0.f) ? Ap[w] : Am[w];
    float c1r = xv.x * Aa.x, c1i = xv.x * Aa.y;
    float c2r = xv.y * Ab.x, c2i = xv.y * Ab.y;
    yt[r][w] = make_float2(c1r - c2i, c1i + c2r);
  }
  __syncthreads();
  {
    const int n = t & 63, rg = t >> 6;
    float2 acc[8] = {};
    for (int w = 0; w < 64; ++w) {
      float lw = l1W[n * 64 + w];
      #pragma unroll
      for (int r = 0; r < 8; ++r) {
        float2 yv = yt[rg * 8 + r][w];
        acc[r].x += yv.x * lw;
        acc[r].y += yv.y * lw;
      }
    }
    float bb = l1b[n];
    #pragma unroll
    for (int r = 0; r < 8; ++r) {
      float zr = acc[r].x + bb; zr = zr > 0.f ? zr : 0.f;
      float zi = acc[r].y;      zi = zi > 0.f ? zi : 0.f;
      zt[rg * 8 + r][n] = make_float2(zr, zi);
    }
  }
  __syncthreads();
  {
    const int j = t & 63, rg = t >> 6;
    float2 acc[8] = {};
    for (int w = 0; w < 64; ++w) {
      float2 qv = Q[j * 64 + w];
      #pragma unroll
      for (int r = 0; r < 8; ++r) {
        float2 zv = zt[rg * 8 + r][w];
        acc[r].x += zv.x * qv.x - zv.y * qv.y;
        acc[r].y += zv.x * qv.y + zv.y * qv.x;
      }
    }
    float2 bc = b2c[j];
    #pragma unroll
    for (int r = 0; r < 8; ++r)
      u[(b0 + rg * 8 + r) * 64 + j] = make_float2(acc[r].x + bc.x, acc[r].y + bc.y);
  }
}

// ---------------------------------------------------------------------------
// Final W_out GEMM; MODE 0 = real only, MODE 1 = interleaved (re,im)
// ---------------------------------------------------------------------------
template<int MODE>
__global__ __launch_bounds__(256) void final_out(
    const float2* __restrict__ v, const float* __restrict__ Wout,
    const float* __restrict__ bout, float* __restrict__ out)
{
  __shared__ float2 vt[64][64];
  const int t = threadIdx.x;
  const size_t b0 = (size_t)blockIdx.x * 64;
  for (int it = 0; it < 16; ++it) {
    int idx = it * 256 + t;
    int r = idx >> 6, w = idx & 63;
    vt[r][w] = v[(b0 + r) * 64 + w];
  }
  __syncthreads();
  const int f = t & 127, rg = t >> 7;
  float2 acc[32] = {};
  for (int j = 0; j < 64; ++j) {
    float wv = Wout[f * 64 + j];
    #pragma unroll
    for (int r = 0; r < 32; ++r) {
      float2 vv = vt[rg * 32 + r][j];
      acc[r].x += vv.x * wv;
      acc[r].y += vv.y * wv;
    }
  }
  float bb = bout[f];
  #pragma unroll
  for (int r = 0; r < 32; ++r) {
    size_t idx = (b0 + rg * 32 + r) * 128 + f;
    if (MODE == 0) out[idx] = acc[r].x + bb;
    else ((float2*)out)[idx] = make_float2(acc[r].x + bb, acc[r].y);
  }
}

// ---------------------------------------------------------------------------
extern "C" void kernel_launch(void* const* d_in, const int* in_sizes, int n_in,
                              void* d_out, int out_size, void* d_ws, size_t ws_size,
                              hipStream_t stream)
{
  (void)in_sizes; (void)n_in; (void)ws_size;
  const float* geom = (const float*)d_in[0];
  const float* Win  = (const float*)d_in[1];
  const float* bin  = (const float*)d_in[2];
  const float* Wh1  = (const float*)d_in[3];
  const float* bh1  = (const float*)d_in[4];
  const float* Wh2  = (const float*)d_in[5];
  const float* bh2  = (const float*)d_in[6];
  const float* w0   = (const float*)d_in[7];
  const float* w1   = (const float*)d_in[8];
  const float* l1W  = (const float*)d_in[9];
  const float* l1b  = (const float*)d_in[10];
  const float* l2W  = (const float*)d_in[11];
  const float* l2b  = (const float*)d_in[12];
  const float* Wout = (const float*)d_in[13];
  const float* bout = (const float*)d_in[14];

  char* ws = (char*)d_ws;
  const size_t MB = 1048576ull;
  unsigned short* geomb = (unsigned short*)(ws);
  unsigned short* x2b   = (unsigned short*)(ws);
  unsigned short* x1b   = (unsigned short*)(ws + 32 * MB);
  float*  x3  = (float*)(ws + 32 * MB);
  float2* S0  = (float2*)(ws + 40 * MB);
  float2* S1  = (float2*)(ws + 56 * MB);
  float2* Ap  = (float2*)(ws + 72 * MB);
  float2* Am  = (float2*)(ws + 72 * MB + 512);
  float2* b2c = (float2*)(ws + 72 * MB + 1024);
  float2* Q   = (float2*)(ws + 72 * MB + 1536);
  unsigned short* Winb = (unsigned short*)(ws + 96 * MB);
  unsigned short* Wh1b = (unsigned short*)(ws + 97 * MB);
  unsigned short* Wh2b = (unsigned short*)(ws + 98 * MB);

  f32_to_bf16_k<<<16384, 256, 0, stream>>>(geom, geomb, 4194304);
  f32_to_bf16_k<<<512, 256, 0, stream>>>(Win, Winb, 131072);
  f32_to_bf16_k<<<512, 256, 0, stream>>>(Wh1, Wh1b, 131072);
  f32_to_bf16_k<<<32, 256, 0, stream>>>(Wh2, Wh2b, 8192);

  gemm_async<128,128,64,64,unsigned short><<<dim3(256, 8), 256, 0, stream>>>(
      geomb, Winb, bin, x1b, 32768, 1024, 512);
  gemm_async<128,128,64,64,unsigned short><<<dim3(256, 4), 256, 0, stream>>>(
      x1b, Wh1b, bh1, x2b, 32768, 512, 1024);
  gemm_async<128, 64,64,32,float><<<dim3(256, 1), 256, 0, stream>>>(
      x2b, Wh2b, bh2, x3, 32768, 64, 512);

  precompute<<<17, 256, 0, stream>>>(w0, w1, l2W, l2b, Ap, Am, Q, b2c);
  dft64_rows<<<512, 256, 0, stream>>>(x3, S0);
  fft_stage1<-1><<<512, 256, 0, stream>>>(S0, S1);
  fft_stage2<-1, false><<<512, 256, 0, stream>>>(S1, S0);
  pw_lin<<<1024, 256, 0, stream>>>(S0, Ap, Am, l1W, l1b, Q, b2c, S1);
  fft_stage1<1><<<512, 256, 0, stream>>>(S1, S0);
  fft_stage2<1, true><<<512, 256, 0, stream>>>(S0, S1);
  if (out_size >= 8388608) {
    final_out<1><<<512, 256, 0, stream>>>(S1, Wout, bout, (float*)d_out);
  } else {
    final_out<0><<<512, 256, 0, stream>>>(S1, Wout, bout, (float*)d_out);
  }
}

// Round 8
// 540.073 us; speedup vs baseline: 2.1991x; 1.0294x over previous
//
#include <hip/hip_runtime.h>
#include <hip/hip_bf16.h>

// ---------------------------------------------------------------------------
// FieldPredictionNetwork. R8: fix scratch-spill in FFT stages.
// R7's phase-A twiddle lookup tw16[(n1*k1p)&15] dynamically indexed a
// REGISTER array (k1p is thread-dependent) -> compiler spilled to scratch
// (VGPR=256, 140MB excess HBM traffic). Phase A now reads twiddles straight
// from the LDS table (broadcast read). Phase B keeps the register copy
// (indices are compile-time). Everything else unchanged from R7.
// ---------------------------------------------------------------------------

#define PI2F 6.28318530717958647692f

typedef __attribute__((ext_vector_type(8))) short short8;
typedef __attribute__((ext_vector_type(4))) float f32x4;

__device__ __forceinline__ unsigned short f2bf(float f) {
  unsigned int u = __float_as_uint(f);
  u += 0x7fff + ((u >> 16) & 1);          // RN-even
  return (unsigned short)(u >> 16);
}
__device__ __forceinline__ unsigned int pack_bf16x2(float a, float b) {
  return (unsigned int)f2bf(a) | ((unsigned int)f2bf(b) << 16);
}

// async 16B global->LDS DMA; lds dest must be wave-uniform (HW adds lane*16)
__device__ __forceinline__ void gl2lds16(const void* gptr, const void* lptr) {
  __builtin_amdgcn_global_load_lds(
      (const __attribute__((address_space(1))) unsigned int*)(unsigned long long)gptr,
      (__attribute__((address_space(3))) unsigned int*)(unsigned int)(unsigned long long)lptr,
      16, 0, 0);
}

// ---------------------------------------------------------------------------
// f32 -> bf16 pack (4 elems/thread)
// ---------------------------------------------------------------------------
__global__ __launch_bounds__(256) void f32_to_bf16_k(
    const float* __restrict__ src, unsigned short* __restrict__ dst, int n4)
{
  int i = blockIdx.x * 256 + threadIdx.x;
  if (i < n4) {
    float4 v = ((const float4*)src)[i];
    uint2 p;
    p.x = pack_bf16x2(v.x, v.y);
    p.y = pack_bf16x2(v.z, v.w);
    ((uint2*)dst)[i] = p;
  }
}

// ---------------------------------------------------------------------------
// GEMM: C = relu(A @ Bw^T + bias). A [M,K] bf16, Bw [N,K] bf16, bias f32.
// OUT = ushort (bf16) or float. BK=64, 4 waves, async LDS staging + swizzle.
// ---------------------------------------------------------------------------
template<int BM, int BN, int WM, int WN, typename OUT>
__global__ __launch_bounds__(256) void gemm_async(
    const unsigned short* __restrict__ A, const unsigned short* __restrict__ Bw,
    const float* __restrict__ bias, OUT* __restrict__ C,
    int M, int N, int K)
{
  constexpr int BK = 64;
  __shared__ __align__(16) unsigned short lA[BM * BK];
  __shared__ __align__(16) unsigned short lB[BN * BK];
  const int tid = threadIdx.x;
  const int lane = tid & 63;
  const int wv = tid >> 6;
  const int q = lane >> 4, lr = lane & 15;
  const int x7 = lr & 7;
  constexpr int WN_CNT = BN / WN;
  const int wm = (wv / WN_CNT) * WM;
  const int wn = (wv % WN_CNT) * WN;
  const size_t m0 = (size_t)blockIdx.x * BM;
  const size_t n0 = (size_t)blockIdx.y * BN;
  constexpr int MI = WM / 16, NI = WN / 16;
  f32x4 acc[MI][NI] = {};
  constexpr int A_INSTR = BM * BK / 512;   // 1024B DMA instructions
  constexpr int B_INSTR = BN * BK / 512;
  constexpr int A_PW = A_INSTR / 4, B_PW = B_INSTR / 4;
  (void)M;

  for (int k0 = 0; k0 < K; k0 += BK) {
    __syncthreads();
    #pragma unroll
    for (int s = 0; s < A_PW; ++s) {
      int instr = wv * A_PW + s;
      int pc = instr * 64 + lane;
      int row = pc >> 3, col = pc & 7;
      int lc = col ^ (row & 7);
      gl2lds16(A + (m0 + row) * K + k0 + lc * 8, lA + instr * 512);
    }
    #pragma unroll
    for (int s = 0; s < B_PW; ++s) {
      int instr = wv * B_PW + s;
      int pc = instr * 64 + lane;
      int row = pc >> 3, col = pc & 7;
      int lc = col ^ (row & 7);
      gl2lds16(Bw + (n0 + row) * K + k0 + lc * 8, lB + instr * 512);
    }
    __syncthreads();
    #pragma unroll
    for (int t = 0; t < 2; ++t) {
      short8 af[MI], bfr[NI];
      #pragma unroll
      for (int i = 0; i < MI; ++i) {
        int r = wm + i * 16 + lr;
        af[i] = *(const short8*)(lA + r * 64 + (((t << 2) | q) ^ x7) * 8);
      }
      #pragma unroll
      for (int j = 0; j < NI; ++j) {
        int r = wn + j * 16 + lr;
        bfr[j] = *(const short8*)(lB + r * 64 + (((t << 2) | q) ^ x7) * 8);
      }
      #pragma unroll
      for (int i = 0; i < MI; ++i)
        #pragma unroll
        for (int j = 0; j < NI; ++j)
          acc[i][j] = __builtin_amdgcn_mfma_f32_16x16x32_bf16(af[i], bfr[j], acc[i][j], 0, 0, 0);
    }
  }
  #pragma unroll
  for (int i = 0; i < MI; ++i)
    #pragma unroll
    for (int j = 0; j < NI; ++j) {
      size_t col = n0 + wn + j * 16 + lr;
      float bv = bias[col];
      #pragma unroll
      for (int r = 0; r < 4; ++r) {
        size_t row = m0 + wm + i * 16 + q * 4 + r;
        float v = acc[i][j][r] + bv;
        v = v > 0.f ? v : 0.f;
        if (sizeof(OUT) == 2) ((unsigned short*)C)[row * N + col] = f2bf(v);
        else                  ((float*)C)[row * N + col] = v;
      }
    }
}

// ---------------------------------------------------------------------------
// Precompute (parallel): block 0 -> Ap/Am/b2c; blocks 1..16 -> Q.
// ---------------------------------------------------------------------------
__global__ __launch_bounds__(256) void precompute(
    const float* __restrict__ w0, const float* __restrict__ w1,
    const float* __restrict__ l2W, const float* __restrict__ l2b,
    float2* __restrict__ Ap, float2* __restrict__ Am,
    float2* __restrict__ Q, float2* __restrict__ b2c)
{
  const int t = threadIdx.x;
  const int blk = blockIdx.x;
  if (blk == 0) {
    if (t < 64) {
      float apx = 0, apy = 0, amx = 0, amy = 0;
      for (int m = 0; m < 32; ++m) {
        float s0 = w0[m * 64 + t];
        float cf = w1[m * 64 + t] * s0;
        float sn, cs; sincosf(PI2F * (float)m / 32.f, &sn, &cs);
        if (s0 > 0.f)      { apx += cs * cf; apy += sn * cf; }
        else if (s0 < 0.f) { amx += cs * cf; amy += sn * cf; }
      }
      Ap[t] = make_float2(apx, apy);
      Am[t] = make_float2(amx, amy);
      float bx = 0, by = 0;
      for (int k = 0; k < 64; ++k) {
        float sn, cs; sincosf(PI2F * (float)((t * k) & 63) / 64.f, &sn, &cs);
        float lb = l2b[k] * (1.f / 64.f);
        bx += cs * lb; by += sn * lb;
      }
      b2c[t] = make_float2(bx, by);
    }
  } else {
    int e = (blk - 1) * 256 + t;
    int j = e >> 6, w = e & 63;
    float qx = 0, qy = 0;
    for (int k = 0; k < 64; ++k) {
      float sn, cs; sincosf(PI2F * (float)((j * k) & 63) / 64.f, &sn, &cs);
      float lw = l2W[k * 64 + w] * (1.f / 64.f);
      qx += cs * lw; qy += sn * lw;
    }
    Q[j * 64 + w] = make_float2(qx, qy);
  }
}

// ---------------------------------------------------------------------------
// DFT along axis1 (64-pt forward)
// ---------------------------------------------------------------------------
__global__ __launch_bounds__(256) void dft64_rows(
    const float* __restrict__ x3, float2* __restrict__ xh1)
{
  __shared__ float xt[64][64];
  __shared__ float2 tw[64];
  const int t = threadIdx.x;
  const size_t b0 = (size_t)blockIdx.x * 64;
  for (int it = 0; it < 16; ++it) {
    int idx = it * 256 + t;
    int r = idx >> 6, w = idx & 63;
    xt[r][w] = x3[(b0 + r) * 64 + w];
  }
  if (t < 64) {
    float sn, cs; sincosf(-PI2F * (float)t / 64.f, &sn, &cs);
    tw[t] = make_float2(cs, sn);
  }
  __syncthreads();
  const int k = t & 63, rg = t >> 6;
  float2 acc[16] = {};
  for (int w = 0; w < 64; ++w) {
    float2 tv = tw[(k * w) & 63];
    #pragma unroll
    for (int r = 0; r < 16; ++r) {
      float xv = xt[rg * 16 + r][w];
      acc[r].x += xv * tv.x;
      acc[r].y += xv * tv.y;
    }
  }
  for (int r = 0; r < 16; ++r)
    xh1[(b0 + rg * 16 + r) * 64 + k] = acc[r];
}

// ---------------------------------------------------------------------------
// Batch-axis FFT stage 1: 128-pt DFT over b1 as radix-16 x radix-8, then
// inter-stage twiddle W32768^{b2*k1} (incremental rotation).
// Phase-A twiddles read from LDS (broadcast) - NOT a register array.
// ---------------------------------------------------------------------------
template<int SIGN>
__global__ __launch_bounds__(256) void fft_stage1(
    const float2* __restrict__ Xin, float2* __restrict__ T)
{
  __shared__ float2 tile[128 * 33];
  __shared__ float2 tw16s[16];
  const int blk = blockIdx.x;
  const int b2 = blk >> 1, wh = (blk & 1) * 32;
  const int t = threadIdx.x;
  for (int it = 0; it < 16; ++it) {
    int idx = it * 256 + t;
    int b1 = idx >> 5, wi = idx & 31;
    tile[b1 * 33 + wi] = Xin[((size_t)(b1 * 256 + b2)) * 64 + wh + wi];
  }
  if (t < 16) {
    float sn, cs; sincosf(SIGN * PI2F * (float)t / 16.f, &sn, &cs);
    tw16s[t] = make_float2(cs, sn);
  }
  __syncthreads();
  // ---- phase A: thread -> pair p=t>>1 (n2=p>>4, k1p=p&15), w0=(t&1)*16
  const int p = t >> 1, n2a = p >> 4, k1pa = p & 15, w0 = (t & 1) * 16;
  float2 ya[16] = {};
  #pragma unroll
  for (int n1 = 0; n1 < 16; ++n1) {
    float2 tv = tw16s[(n1 * k1pa) & 15];       // LDS broadcast (runtime idx OK)
    const float2* row = &tile[(8 * n1 + n2a) * 33 + w0];
    #pragma unroll
    for (int w = 0; w < 16; ++w) {
      float2 d = row[w];
      ya[w].x += d.x * tv.x - d.y * tv.y;
      ya[w].y += d.x * tv.y + d.y * tv.x;
    }
  }
  {
    float sn, cs; sincosf(SIGN * PI2F * (float)(n2a * k1pa) / 128.f, &sn, &cs);
    #pragma unroll
    for (int w = 0; w < 16; ++w) {
      float2 a = ya[w];
      ya[w] = make_float2(a.x * cs - a.y * sn, a.x * sn + a.y * cs);
    }
  }
  __syncthreads();                       // all phase-A reads of tile done
  {
    float2* yrow = &tile[(n2a * 16 + k1pa) * 33 + w0];
    #pragma unroll
    for (int w = 0; w < 16; ++w) yrow[w] = ya[w];
  }
  __syncthreads();                       // y visible
  // ---- phase B: thread -> (w = t&31, q = t>>5); k1p in {q, q+8}
  const int wB = t & 31, qB = t >> 5;
  float2 w8[8];
  #pragma unroll
  for (int j = 0; j < 8; ++j) w8[j] = tw16s[2 * j];   // static idx -> regs OK
  float sstep, cstep;
  sincosf(SIGN * PI2F * (float)(16 * b2) / 32768.f, &sstep, &cstep);
  #pragma unroll
  for (int h = 0; h < 2; ++h) {
    const int k1p = qB + 8 * h;
    float2 acc[8] = {};
    #pragma unroll
    for (int n2 = 0; n2 < 8; ++n2) {
      float2 d = tile[(n2 * 16 + k1p) * 33 + wB];
      #pragma unroll
      for (int k2p = 0; k2p < 8; ++k2p) {
        float2 tv = w8[(n2 * k2p) & 7];          // static idx
        acc[k2p].x += d.x * tv.x - d.y * tv.y;
        acc[k2p].y += d.x * tv.y + d.y * tv.x;
      }
    }
    float sb, cb;
    sincosf(SIGN * PI2F * (float)(b2 * k1p) / 32768.f, &sb, &cb);
    float2 rot = make_float2(cb, sb);
    #pragma unroll
    for (int k2p = 0; k2p < 8; ++k2p) {
      int k1 = k1p + 16 * k2p;
      float2 a = acc[k2p];
      float2 o = make_float2(a.x * rot.x - a.y * rot.y,
                             a.x * rot.y + a.y * rot.x);
      T[((size_t)k1 * 256 + b2) * 64 + wh + wB] = o;
      float nrx = rot.x * cstep - rot.y * sstep;
      rot.y = rot.x * sstep + rot.y * cstep;
      rot.x = nrx;
    }
  }
}

// ---------------------------------------------------------------------------
// Batch-axis FFT stage 2: 256-pt DFT over b2 as radix-16 x radix-16.
// Phase-A twiddles read from LDS (broadcast) - NOT a register array.
// ---------------------------------------------------------------------------
template<int SIGN, bool SCALE>
__global__ __launch_bounds__(256) void fft_stage2(
    const float2* __restrict__ T, float2* __restrict__ X)
{
  __shared__ float2 tile[256 * 17];
  __shared__ float2 tw16s[16];
  const int blk = blockIdx.x;
  const int k1 = blk >> 2, wq = (blk & 3) * 16;
  const int t = threadIdx.x;
  for (int it = 0; it < 16; ++it) {
    int idx = it * 256 + t;
    int r2 = idx >> 4, wi = idx & 15;
    tile[r2 * 17 + wi] = T[((size_t)k1 * 256 + r2) * 64 + wq + wi];
  }
  if (t < 16) {
    float sn, cs; sincosf(SIGN * PI2F * (float)t / 16.f, &sn, &cs);
    tw16s[t] = make_float2(cs, sn);
  }
  __syncthreads();
  // ---- phase A: thread -> (n2 = t>>4, k1p = t&15)
  const int n2a = t >> 4, k1pa = t & 15;
  float2 ya[16] = {};
  #pragma unroll
  for (int n1 = 0; n1 < 16; ++n1) {
    float2 tv = tw16s[(n1 * k1pa) & 15];       // LDS broadcast (runtime idx OK)
    const float2* row = &tile[(16 * n1 + n2a) * 17];
    #pragma unroll
    for (int w = 0; w < 16; ++w) {
      float2 d = row[w];
      ya[w].x += d.x * tv.x - d.y * tv.y;
      ya[w].y += d.x * tv.y + d.y * tv.x;
    }
  }
  {
    float sn, cs; sincosf(SIGN * PI2F * (float)(n2a * k1pa) / 256.f, &sn, &cs);
    #pragma unroll
    for (int w = 0; w < 16; ++w) {
      float2 a = ya[w];
      ya[w] = make_float2(a.x * cs - a.y * sn, a.x * sn + a.y * cs);
    }
  }
  __syncthreads();                       // all phase-A reads done
  {
    float2* yrow = &tile[(n2a * 16 + k1pa) * 17];
    #pragma unroll
    for (int w = 0; w < 16; ++w) yrow[w] = ya[w];
  }
  __syncthreads();                       // y visible
  // ---- phase B: thread -> (k1p = t>>4, w = t&15)
  const int k1pb = t >> 4, wB = t & 15;
  float2 tw16[16];
  #pragma unroll
  for (int j = 0; j < 16; ++j) tw16[j] = tw16s[j];   // static idx -> regs OK
  float2 acc[16] = {};
  #pragma unroll
  for (int n2 = 0; n2 < 16; ++n2) {
    float2 d = tile[(n2 * 16 + k1pb) * 17 + wB];
    #pragma unroll
    for (int k2p = 0; k2p < 16; ++k2p) {
      float2 tv = tw16[(n2 * k2p) & 15];       // static idx
      acc[k2p].x += d.x * tv.x - d.y * tv.y;
      acc[k2p].y += d.x * tv.y + d.y * tv.x;
    }
  }
  const float sc = SCALE ? (1.f / 32768.f) : 1.f;
  #pragma unroll
  for (int k2p = 0; k2p < 16; ++k2p) {
    int k2 = k1pb + 16 * k2p;
    size_t row = (size_t)(k1 + 128 * k2);
    X[row * 64 + wq + wB] = make_float2(acc[k2p].x * sc, acc[k2p].y * sc);
  }
}

// ---------------------------------------------------------------------------
// Pointwise A+/- fold, lin1 crelu, Q-fold (ifft64+lin2)
// ---------------------------------------------------------------------------
__global__ __launch_bounds__(256) void pw_lin(
    const float2* __restrict__ xh,
    const float2* __restrict__ Ap, const float2* __restrict__ Am,
    const float* __restrict__ l1W, const float* __restrict__ l1b,
    const float2* __restrict__ Q, const float2* __restrict__ b2c,
    float2* __restrict__ u)
{
  __shared__ float2 yt[32][64];
  __shared__ float2 zt[32][64];
  const int t = threadIdx.x;
  const size_t b0 = (size_t)blockIdx.x * 32;
  for (int it = 0; it < 8; ++it) {
    int idx = it * 256 + t;
    int r = idx >> 6, w = idx & 63;
    float2 xv = xh[(b0 + r) * 64 + w];
    float2 Aa = (xv.x >= 0.f) ? Ap[w] : Am[w];
    float2 Ab = (xv.y >= 0.f) ? Ap[w] : Am[w];
    float c1r = xv.x * Aa.x, c1i = xv.x * Aa.y;
    float c2r = xv.y * Ab.x, c2i = xv.y * Ab.y;
    yt[r][w] = make_float2(c1r - c2i, c1i + c2r);
  }
  __syncthreads();
  {
    const int n = t & 63, rg = t >> 6;
    float2 acc[8] = {};
    for (int w = 0; w < 64; ++w) {
      float lw = l1W[n * 64 + w];
      #pragma unroll
      for (int r = 0; r < 8; ++r) {
        float2 yv = yt[rg * 8 + r][w];
        acc[r].x += yv.x * lw;
        acc[r].y += yv.y * lw;
      }
    }
    float bb = l1b[n];
    #pragma unroll
    for (int r = 0; r < 8; ++r) {
      float zr = acc[r].x + bb; zr = zr > 0.f ? zr : 0.f;
      float zi = acc[r].y;      zi = zi > 0.f ? zi : 0.f;
      zt[rg * 8 + r][n] = make_float2(zr, zi);
    }
  }
  __syncthreads();
  {
    const int j = t & 63, rg = t >> 6;
    float2 acc[8] = {};
    for (int w = 0; w < 64; ++w) {
      float2 qv = Q[j * 64 + w];
      #pragma unroll
      for (int r = 0; r < 8; ++r) {
        float2 zv = zt[rg * 8 + r][w];
        acc[r].x += zv.x * qv.x - zv.y * qv.y;
        acc[r].y += zv.x * qv.y + zv.y * qv.x;
      }
    }
    float2 bc = b2c[j];
    #pragma unroll
    for (int r = 0; r < 8; ++r)
      u[(b0 + rg * 8 + r) * 64 + j] = make_float2(acc[r].x + bc.x, acc[r].y + bc.y);
  }
}

// ---------------------------------------------------------------------------
// Final W_out GEMM; MODE 0 = real only, MODE 1 = interleaved (re,im)
// ---------------------------------------------------------------------------
template<int MODE>
__global__ __launch_bounds__(256) void final_out(
    const float2* __restrict__ v, const float* __restrict__ Wout,
    const float* __restrict__ bout, float* __restrict__ out)
{
  __shared__ float2 vt[64][64];
  const int t = threadIdx.x;
  const size_t b0 = (size_t)blockIdx.x * 64;
  for (int it = 0; it < 16; ++it) {
    int idx = it * 256 + t;
    int r = idx >> 6, w = idx & 63;
    vt[r][w] = v[(b0 + r) * 64 + w];
  }
  __syncthreads();
  const int f = t & 127, rg = t >> 7;
  float2 acc[32] = {};
  for (int j = 0; j < 64; ++j) {
    float wv = Wout[f * 64 + j];
    #pragma unroll
    for (int r = 0; r < 32; ++r) {
      float2 vv = vt[rg * 32 + r][j];
      acc[r].x += vv.x * wv;
      acc[r].y += vv.y * wv;
    }
  }
  float bb = bout[f];
  #pragma unroll
  for (int r = 0; r < 32; ++r) {
    size_t idx = (b0 + rg * 32 + r) * 128 + f;
    if (MODE == 0) out[idx] = acc[r].x + bb;
    else ((float2*)out)[idx] = make_float2(acc[r].x + bb, acc[r].y);
  }
}

// ---------------------------------------------------------------------------
extern "C" void kernel_launch(void* const* d_in, const int* in_sizes, int n_in,
                              void* d_out, int out_size, void* d_ws, size_t ws_size,
                              hipStream_t stream)
{
  (void)in_sizes; (void)n_in; (void)ws_size;
  const float* geom = (const float*)d_in[0];
  const float* Win  = (const float*)d_in[1];
  const float* bin  = (const float*)d_in[2];
  const float* Wh1  = (const float*)d_in[3];
  const float* bh1  = (const float*)d_in[4];
  const float* Wh2  = (const float*)d_in[5];
  const float* bh2  = (const float*)d_in[6];
  const float* w0   = (const float*)d_in[7];
  const float* w1   = (const float*)d_in[8];
  const float* l1W  = (const float*)d_in[9];
  const float* l1b  = (const float*)d_in[10];
  const float* l2W  = (const float*)d_in[11];
  const float* l2b  = (const float*)d_in[12];
  const float* Wout = (const float*)d_in[13];
  const float* bout = (const float*)d_in[14];

  char* ws = (char*)d_ws;
  const size_t MB = 1048576ull;
  unsigned short* geomb = (unsigned short*)(ws);
  unsigned short* x2b   = (unsigned short*)(ws);
  unsigned short* x1b   = (unsigned short*)(ws + 32 * MB);
  float*  x3  = (float*)(ws + 32 * MB);
  float2* S0  = (float2*)(ws + 40 * MB);
  float2* S1  = (float2*)(ws + 56 * MB);
  float2* Ap  = (float2*)(ws + 72 * MB);
  float2* Am  = (float2*)(ws + 72 * MB + 512);
  float2* b2c = (float2*)(ws + 72 * MB + 1024);
  float2* Q   = (float2*)(ws + 72 * MB + 1536);
  unsigned short* Winb = (unsigned short*)(ws + 96 * MB);
  unsigned short* Wh1b = (unsigned short*)(ws + 97 * MB);
  unsigned short* Wh2b = (unsigned short*)(ws + 98 * MB);

  f32_to_bf16_k<<<16384, 256, 0, stream>>>(geom, geomb, 4194304);
  f32_to_bf16_k<<<512, 256, 0, stream>>>(Win, Winb, 131072);
  f32_to_bf16_k<<<512, 256, 0, stream>>>(Wh1, Wh1b, 131072);
  f32_to_bf16_k<<<32, 256, 0, stream>>>(Wh2, Wh2b, 8192);

  gemm_async<128,128,64,64,unsigned short><<<dim3(256, 8), 256, 0, stream>>>(
      geomb, Winb, bin, x1b, 32768, 1024, 512);
  gemm_async<128,128,64,64,unsigned short><<<dim3(256, 4), 256, 0, stream>>>(
      x1b, Wh1b, bh1, x2b, 32768, 512, 1024);
  gemm_async<128, 64,64,32,float><<<dim3(256, 1), 256, 0, stream>>>(
      x2b, Wh2b, bh2, x3, 32768, 64, 512);

  precompute<<<17, 256, 0, stream>>>(w0, w1, l2W, l2b, Ap, Am, Q, b2c);
  dft64_rows<<<512, 256, 0, stream>>>(x3, S0);
  fft_stage1<-1><<<512, 256, 0, stream>>>(S0, S1);
  fft_stage2<-1, false><<<512, 256, 0, stream>>>(S1, S0);
  pw_lin<<<1024, 256, 0, stream>>>(S0, Ap, Am, l1W, l1b, Q, b2c, S1);
  fft_stage1<1><<<512, 256, 0, stream>>>(S1, S0);
  fft_stage2<1, true><<<512, 256, 0, stream>>>(S0, S1);
  if (out_size >= 8388608) {
    final_out<1><<<512, 256, 0, stream>>>(S1, Wout, bout, (float*)d_out);
  } else {
    final_out<0><<<512, 256, 0, stream>>>(S1, Wout, bout, (float*)d_out);
  }
}

// Round 9
// 482.222 us; speedup vs baseline: 2.4629x; 1.1200x over previous
//
#include <hip/hip_runtime.h>
#include <hip/hip_bf16.h>

// ---------------------------------------------------------------------------
// FieldPredictionNetwork. R9: kill the FFT-stage scratch spill for real.
// R8 evidence: VGPR=256 persisted after removing dynamic register indexing ->
// the spill is UNROLL pressure (phase A fully unrolled n1 x w = 256 cmacs,
// 128 ds_read results hoisted). Fix: #pragma unroll 1 on outer accumulation
// loops; phase-B twiddles via LDS since their loop var is now rolled
// (register-array indices must stay compile-time). ~90 VGPR, no scratch ->
// also removes the 126us first-dispatch scratch-setup stall seen at _ord 0.
// ---------------------------------------------------------------------------

#define PI2F 6.28318530717958647692f

typedef __attribute__((ext_vector_type(8))) short short8;
typedef __attribute__((ext_vector_type(4))) float f32x4;

__device__ __forceinline__ unsigned short f2bf(float f) {
  unsigned int u = __float_as_uint(f);
  u += 0x7fff + ((u >> 16) & 1);          // RN-even
  return (unsigned short)(u >> 16);
}
__device__ __forceinline__ unsigned int pack_bf16x2(float a, float b) {
  return (unsigned int)f2bf(a) | ((unsigned int)f2bf(b) << 16);
}

// async 16B global->LDS DMA; lds dest must be wave-uniform (HW adds lane*16)
__device__ __forceinline__ void gl2lds16(const void* gptr, const void* lptr) {
  __builtin_amdgcn_global_load_lds(
      (const __attribute__((address_space(1))) unsigned int*)(unsigned long long)gptr,
      (__attribute__((address_space(3))) unsigned int*)(unsigned int)(unsigned long long)lptr,
      16, 0, 0);
}

// ---------------------------------------------------------------------------
// f32 -> bf16 pack (4 elems/thread)
// ---------------------------------------------------------------------------
__global__ __launch_bounds__(256) void f32_to_bf16_k(
    const float* __restrict__ src, unsigned short* __restrict__ dst, int n4)
{
  int i = blockIdx.x * 256 + threadIdx.x;
  if (i < n4) {
    float4 v = ((const float4*)src)[i];
    uint2 p;
    p.x = pack_bf16x2(v.x, v.y);
    p.y = pack_bf16x2(v.z, v.w);
    ((uint2*)dst)[i] = p;
  }
}

// ---------------------------------------------------------------------------
// GEMM: C = relu(A @ Bw^T + bias). A [M,K] bf16, Bw [N,K] bf16, bias f32.
// OUT = ushort (bf16) or float. BK=64, 4 waves, async LDS staging + swizzle.
// ---------------------------------------------------------------------------
template<int BM, int BN, int WM, int WN, typename OUT>
__global__ __launch_bounds__(256) void gemm_async(
    const unsigned short* __restrict__ A, const unsigned short* __restrict__ Bw,
    const float* __restrict__ bias, OUT* __restrict__ C,
    int M, int N, int K)
{
  constexpr int BK = 64;
  __shared__ __align__(16) unsigned short lA[BM * BK];
  __shared__ __align__(16) unsigned short lB[BN * BK];
  const int tid = threadIdx.x;
  const int lane = tid & 63;
  const int wv = tid >> 6;
  const int q = lane >> 4, lr = lane & 15;
  const int x7 = lr & 7;
  constexpr int WN_CNT = BN / WN;
  const int wm = (wv / WN_CNT) * WM;
  const int wn = (wv % WN_CNT) * WN;
  const size_t m0 = (size_t)blockIdx.x * BM;
  const size_t n0 = (size_t)blockIdx.y * BN;
  constexpr int MI = WM / 16, NI = WN / 16;
  f32x4 acc[MI][NI] = {};
  constexpr int A_INSTR = BM * BK / 512;   // 1024B DMA instructions
  constexpr int B_INSTR = BN * BK / 512;
  constexpr int A_PW = A_INSTR / 4, B_PW = B_INSTR / 4;
  (void)M;

  for (int k0 = 0; k0 < K; k0 += BK) {
    __syncthreads();
    #pragma unroll
    for (int s = 0; s < A_PW; ++s) {
      int instr = wv * A_PW + s;
      int pc = instr * 64 + lane;
      int row = pc >> 3, col = pc & 7;
      int lc = col ^ (row & 7);
      gl2lds16(A + (m0 + row) * K + k0 + lc * 8, lA + instr * 512);
    }
    #pragma unroll
    for (int s = 0; s < B_PW; ++s) {
      int instr = wv * B_PW + s;
      int pc = instr * 64 + lane;
      int row = pc >> 3, col = pc & 7;
      int lc = col ^ (row & 7);
      gl2lds16(Bw + (n0 + row) * K + k0 + lc * 8, lB + instr * 512);
    }
    __syncthreads();
    #pragma unroll
    for (int t = 0; t < 2; ++t) {
      short8 af[MI], bfr[NI];
      #pragma unroll
      for (int i = 0; i < MI; ++i) {
        int r = wm + i * 16 + lr;
        af[i] = *(const short8*)(lA + r * 64 + (((t << 2) | q) ^ x7) * 8);
      }
      #pragma unroll
      for (int j = 0; j < NI; ++j) {
        int r = wn + j * 16 + lr;
        bfr[j] = *(const short8*)(lB + r * 64 + (((t << 2) | q) ^ x7) * 8);
      }
      #pragma unroll
      for (int i = 0; i < MI; ++i)
        #pragma unroll
        for (int j = 0; j < NI; ++j)
          acc[i][j] = __builtin_amdgcn_mfma_f32_16x16x32_bf16(af[i], bfr[j], acc[i][j], 0, 0, 0);
    }
  }
  #pragma unroll
  for (int i = 0; i < MI; ++i)
    #pragma unroll
    for (int j = 0; j < NI; ++j) {
      size_t col = n0 + wn + j * 16 + lr;
      float bv = bias[col];
      #pragma unroll
      for (int r = 0; r < 4; ++r) {
        size_t row = m0 + wm + i * 16 + q * 4 + r;
        float v = acc[i][j][r] + bv;
        v = v > 0.f ? v : 0.f;
        if (sizeof(OUT) == 2) ((unsigned short*)C)[row * N + col] = f2bf(v);
        else                  ((float*)C)[row * N + col] = v;
      }
    }
}

// ---------------------------------------------------------------------------
// Precompute (parallel): block 0 -> Ap/Am/b2c; blocks 1..16 -> Q.
// ---------------------------------------------------------------------------
__global__ __launch_bounds__(256) void precompute(
    const float* __restrict__ w0, const float* __restrict__ w1,
    const float* __restrict__ l2W, const float* __restrict__ l2b,
    float2* __restrict__ Ap, float2* __restrict__ Am,
    float2* __restrict__ Q, float2* __restrict__ b2c)
{
  const int t = threadIdx.x;
  const int blk = blockIdx.x;
  if (blk == 0) {
    if (t < 64) {
      float apx = 0, apy = 0, amx = 0, amy = 0;
      for (int m = 0; m < 32; ++m) {
        float s0 = w0[m * 64 + t];
        float cf = w1[m * 64 + t] * s0;
        float sn, cs; sincosf(PI2F * (float)m / 32.f, &sn, &cs);
        if (s0 > 0.f)      { apx += cs * cf; apy += sn * cf; }
        else if (s0 < 0.f) { amx += cs * cf; amy += sn * cf; }
      }
      Ap[t] = make_float2(apx, apy);
      Am[t] = make_float2(amx, amy);
      float bx = 0, by = 0;
      for (int k = 0; k < 64; ++k) {
        float sn, cs; sincosf(PI2F * (float)((t * k) & 63) / 64.f, &sn, &cs);
        float lb = l2b[k] * (1.f / 64.f);
        bx += cs * lb; by += sn * lb;
      }
      b2c[t] = make_float2(bx, by);
    }
  } else {
    int e = (blk - 1) * 256 + t;
    int j = e >> 6, w = e & 63;
    float qx = 0, qy = 0;
    for (int k = 0; k < 64; ++k) {
      float sn, cs; sincosf(PI2F * (float)((j * k) & 63) / 64.f, &sn, &cs);
      float lw = l2W[k * 64 + w] * (1.f / 64.f);
      qx += cs * lw; qy += sn * lw;
    }
    Q[j * 64 + w] = make_float2(qx, qy);
  }
}

// ---------------------------------------------------------------------------
// DFT along axis1 (64-pt forward)
// ---------------------------------------------------------------------------
__global__ __launch_bounds__(256) void dft64_rows(
    const float* __restrict__ x3, float2* __restrict__ xh1)
{
  __shared__ float xt[64][64];
  __shared__ float2 tw[64];
  const int t = threadIdx.x;
  const size_t b0 = (size_t)blockIdx.x * 64;
  for (int it = 0; it < 16; ++it) {
    int idx = it * 256 + t;
    int r = idx >> 6, w = idx & 63;
    xt[r][w] = x3[(b0 + r) * 64 + w];
  }
  if (t < 64) {
    float sn, cs; sincosf(-PI2F * (float)t / 64.f, &sn, &cs);
    tw[t] = make_float2(cs, sn);
  }
  __syncthreads();
  const int k = t & 63, rg = t >> 6;
  float2 acc[16] = {};
  #pragma unroll 1
  for (int w = 0; w < 64; ++w) {
    float2 tv = tw[(k * w) & 63];
    #pragma unroll
    for (int r = 0; r < 16; ++r) {
      float xv = xt[rg * 16 + r][w];
      acc[r].x += xv * tv.x;
      acc[r].y += xv * tv.y;
    }
  }
  for (int r = 0; r < 16; ++r)
    xh1[(b0 + rg * 16 + r) * 64 + k] = acc[r];
}

// ---------------------------------------------------------------------------
// Batch-axis FFT stage 1: 128-pt DFT over b1 as radix-16 x radix-8, then
// inter-stage twiddle W32768^{b2*k1} (incremental rotation).
// Outer accumulation loops ROLLED (unroll 1) to bound register pressure;
// all twiddle lookups with runtime indices go through LDS.
// ---------------------------------------------------------------------------
template<int SIGN>
__global__ __launch_bounds__(256) void fft_stage1(
    const float2* __restrict__ Xin, float2* __restrict__ T)
{
  __shared__ float2 tile[128 * 33];
  __shared__ float2 tw16s[16];
  const int blk = blockIdx.x;
  const int b2 = blk >> 1, wh = (blk & 1) * 32;
  const int t = threadIdx.x;
  for (int it = 0; it < 16; ++it) {
    int idx = it * 256 + t;
    int b1 = idx >> 5, wi = idx & 31;
    tile[b1 * 33 + wi] = Xin[((size_t)(b1 * 256 + b2)) * 64 + wh + wi];
  }
  if (t < 16) {
    float sn, cs; sincosf(SIGN * PI2F * (float)t / 16.f, &sn, &cs);
    tw16s[t] = make_float2(cs, sn);
  }
  __syncthreads();
  // ---- phase A: thread -> pair p=t>>1 (n2=p>>4, k1p=p&15), w0=(t&1)*16
  const int p = t >> 1, n2a = p >> 4, k1pa = p & 15, w0 = (t & 1) * 16;
  float2 ya[16] = {};
  #pragma unroll 1
  for (int n1 = 0; n1 < 16; ++n1) {
    float2 tv = tw16s[(n1 * k1pa) & 15];       // LDS broadcast
    const float2* row = &tile[(8 * n1 + n2a) * 33 + w0];
    #pragma unroll
    for (int w = 0; w < 16; ++w) {
      float2 d = row[w];
      ya[w].x += d.x * tv.x - d.y * tv.y;
      ya[w].y += d.x * tv.y + d.y * tv.x;
    }
  }
  {
    float sn, cs; sincosf(SIGN * PI2F * (float)(n2a * k1pa) / 128.f, &sn, &cs);
    #pragma unroll
    for (int w = 0; w < 16; ++w) {
      float2 a = ya[w];
      ya[w] = make_float2(a.x * cs - a.y * sn, a.x * sn + a.y * cs);
    }
  }
  __syncthreads();                       // all phase-A reads of tile done
  {
    float2* yrow = &tile[(n2a * 16 + k1pa) * 33 + w0];
    #pragma unroll
    for (int w = 0; w < 16; ++w) yrow[w] = ya[w];
  }
  __syncthreads();                       // y visible
  // ---- phase B: thread -> (w = t&31, q = t>>5); k1p in {q, q+8}
  const int wB = t & 31, qB = t >> 5;
  float sstep, cstep;
  sincosf(SIGN * PI2F * (float)(16 * b2) / 32768.f, &sstep, &cstep);
  #pragma unroll 1
  for (int h = 0; h < 2; ++h) {
    const int k1p = qB + 8 * h;
    float2 acc[8] = {};
    #pragma unroll 1
    for (int n2 = 0; n2 < 8; ++n2) {
      float2 d = tile[(n2 * 16 + k1p) * 33 + wB];
      #pragma unroll
      for (int k2p = 0; k2p < 8; ++k2p) {
        float2 tv = tw16s[(2 * n2 * k2p) & 15];  // W8^{n2 k2p}, LDS broadcast
        acc[k2p].x += d.x * tv.x - d.y * tv.y;
        acc[k2p].y += d.x * tv.y + d.y * tv.x;
      }
    }
    float sb, cb;
    sincosf(SIGN * PI2F * (float)(b2 * k1p) / 32768.f, &sb, &cb);
    float2 rot = make_float2(cb, sb);
    #pragma unroll
    for (int k2p = 0; k2p < 8; ++k2p) {
      int k1 = k1p + 16 * k2p;
      float2 a = acc[k2p];
      float2 o = make_float2(a.x * rot.x - a.y * rot.y,
                             a.x * rot.y + a.y * rot.x);
      T[((size_t)k1 * 256 + b2) * 64 + wh + wB] = o;
      float nrx = rot.x * cstep - rot.y * sstep;
      rot.y = rot.x * sstep + rot.y * cstep;
      rot.x = nrx;
    }
  }
}

// ---------------------------------------------------------------------------
// Batch-axis FFT stage 2: 256-pt DFT over b2 as radix-16 x radix-16.
// Outer accumulation loops ROLLED; twiddles via LDS.
// ---------------------------------------------------------------------------
template<int SIGN, bool SCALE>
__global__ __launch_bounds__(256) void fft_stage2(
    const float2* __restrict__ T, float2* __restrict__ X)
{
  __shared__ float2 tile[256 * 17];
  __shared__ float2 tw16s[16];
  const int blk = blockIdx.x;
  const int k1 = blk >> 2, wq = (blk & 3) * 16;
  const int t = threadIdx.x;
  for (int it = 0; it < 16; ++it) {
    int idx = it * 256 + t;
    int r2 = idx >> 4, wi = idx & 15;
    tile[r2 * 17 + wi] = T[((size_t)k1 * 256 + r2) * 64 + wq + wi];
  }
  if (t < 16) {
    float sn, cs; sincosf(SIGN * PI2F * (float)t / 16.f, &sn, &cs);
    tw16s[t] = make_float2(cs, sn);
  }
  __syncthreads();
  // ---- phase A: thread -> (n2 = t>>4, k1p = t&15)
  const int n2a = t >> 4, k1pa = t & 15;
  float2 ya[16] = {};
  #pragma unroll 1
  for (int n1 = 0; n1 < 16; ++n1) {
    float2 tv = tw16s[(n1 * k1pa) & 15];       // LDS broadcast
    const float2* row = &tile[(16 * n1 + n2a) * 17];
    #pragma unroll
    for (int w = 0; w < 16; ++w) {
      float2 d = row[w];
      ya[w].x += d.x * tv.x - d.y * tv.y;
      ya[w].y += d.x * tv.y + d.y * tv.x;
    }
  }
  {
    float sn, cs; sincosf(SIGN * PI2F * (float)(n2a * k1pa) / 256.f, &sn, &cs);
    #pragma unroll
    for (int w = 0; w < 16; ++w) {
      float2 a = ya[w];
      ya[w] = make_float2(a.x * cs - a.y * sn, a.x * sn + a.y * cs);
    }
  }
  __syncthreads();                       // all phase-A reads done
  {
    float2* yrow = &tile[(n2a * 16 + k1pa) * 17];
    #pragma unroll
    for (int w = 0; w < 16; ++w) yrow[w] = ya[w];
  }
  __syncthreads();                       // y visible
  // ---- phase B: thread -> (k1p = t>>4, w = t&15)
  const int k1pb = t >> 4, wB = t & 15;
  float2 acc[16] = {};
  #pragma unroll 1
  for (int n2 = 0; n2 < 16; ++n2) {
    float2 d = tile[(n2 * 16 + k1pb) * 17 + wB];
    #pragma unroll
    for (int k2p = 0; k2p < 16; ++k2p) {
      float2 tv = tw16s[(n2 * k2p) & 15];      // LDS broadcast
      acc[k2p].x += d.x * tv.x - d.y * tv.y;
      acc[k2p].y += d.x * tv.y + d.y * tv.x;
    }
  }
  const float sc = SCALE ? (1.f / 32768.f) : 1.f;
  #pragma unroll
  for (int k2p = 0; k2p < 16; ++k2p) {
    int k2 = k1pb + 16 * k2p;
    size_t row = (size_t)(k1 + 128 * k2);
    X[row * 64 + wq + wB] = make_float2(acc[k2p].x * sc, acc[k2p].y * sc);
  }
}

// ---------------------------------------------------------------------------
// Pointwise A+/- fold, lin1 crelu, Q-fold (ifft64+lin2)
// ---------------------------------------------------------------------------
__global__ __launch_bounds__(256) void pw_lin(
    const float2* __restrict__ xh,
    const float2* __restrict__ Ap, const float2* __restrict__ Am,
    const float* __restrict__ l1W, const float* __restrict__ l1b,
    const float2* __restrict__ Q, const float2* __restrict__ b2c,
    float2* __restrict__ u)
{
  __shared__ float2 yt[32][64];
  __shared__ float2 zt[32][64];
  const int t = threadIdx.x;
  const size_t b0 = (size_t)blockIdx.x * 32;
  for (int it = 0; it < 8; ++it) {
    int idx = it * 256 + t;
    int r = idx >> 6, w = idx & 63;
    float2 xv = xh[(b0 + r) * 64 + w];
    float2 Aa = (xv.x >= 0.f) ? Ap[w] : Am[w];
    float2 Ab = (xv.y >= 0.f) ? Ap[w] : Am[w];
    float c1r = xv.x * Aa.x, c1i = xv.x * Aa.y;
    float c2r = xv.y * Ab.x, c2i = xv.y * Ab.y;
    yt[r][w] = make_float2(c1r - c2i, c1i + c2r);
  }
  __syncthreads();
  {
    const int n = t & 63, rg = t >> 6;
    float2 acc[8] = {};
    #pragma unroll 1
    for (int w = 0; w < 64; ++w) {
      float lw = l1W[n * 64 + w];
      #pragma unroll
      for (int r = 0; r < 8; ++r) {
        float2 yv = yt[rg * 8 + r][w];
        acc[r].x += yv.x * lw;
        acc[r].y += yv.y * lw;
      }
    }
    float bb = l1b[n];
    #pragma unroll
    for (int r = 0; r < 8; ++r) {
      float zr = acc[r].x + bb; zr = zr > 0.f ? zr : 0.f;
      float zi = acc[r].y;      zi = zi > 0.f ? zi : 0.f;
      zt[rg * 8 + r][n] = make_float2(zr, zi);
    }
  }
  __syncthreads();
  {
    const int j = t & 63, rg = t >> 6;
    float2 acc[8] = {};
    #pragma unroll 1
    for (int w = 0; w < 64; ++w) {
      float2 qv = Q[j * 64 + w];
      #pragma unroll
      for (int r = 0; r < 8; ++r) {
        float2 zv = zt[rg * 8 + r][w];
        acc[r].x += zv.x * qv.x - zv.y * qv.y;
        acc[r].y += zv.x * qv.y + zv.y * qv.x;
      }
    }
    float2 bc = b2c[j];
    #pragma unroll
    for (int r = 0; r < 8; ++r)
      u[(b0 + rg * 8 + r) * 64 + j] = make_float2(acc[r].x + bc.x, acc[r].y + bc.y);
  }
}

// ---------------------------------------------------------------------------
// Final W_out GEMM; MODE 0 = real only, MODE 1 = interleaved (re,im)
// ---------------------------------------------------------------------------
template<int MODE>
__global__ __launch_bounds__(256) void final_out(
    const float2* __restrict__ v, const float* __restrict__ Wout,
    const float* __restrict__ bout, float* __restrict__ out)
{
  __shared__ float2 vt[64][64];
  const int t = threadIdx.x;
  const size_t b0 = (size_t)blockIdx.x * 64;
  for (int it = 0; it < 16; ++it) {
    int idx = it * 256 + t;
    int r = idx >> 6, w = idx & 63;
    vt[r][w] = v[(b0 + r) * 64 + w];
  }
  __syncthreads();
  const int f = t & 127, rg = t >> 7;
  float2 acc[32] = {};
  #pragma unroll 1
  for (int j = 0; j < 64; ++j) {
    float wv = Wout[f * 64 + j];
    #pragma unroll
    for (int r = 0; r < 32; ++r) {
      float2 vv = vt[rg * 32 + r][j];
      acc[r].x += vv.x * wv;
      acc[r].y += vv.y * wv;
    }
  }
  float bb = bout[f];
  #pragma unroll
  for (int r = 0; r < 32; ++r) {
    size_t idx = (b0 + rg * 32 + r) * 128 + f;
    if (MODE == 0) out[idx] = acc[r].x + bb;
    else ((float2*)out)[idx] = make_float2(acc[r].x + bb, acc[r].y);
  }
}

// ---------------------------------------------------------------------------
extern "C" void kernel_launch(void* const* d_in, const int* in_sizes, int n_in,
                              void* d_out, int out_size, void* d_ws, size_t ws_size,
                              hipStream_t stream)
{
  (void)in_sizes; (void)n_in; (void)ws_size;
  const float* geom = (const float*)d_in[0];
  const float* Win  = (const float*)d_in[1];
  const float* bin  = (const float*)d_in[2];
  const float* Wh1  = (const float*)d_in[3];
  const float* bh1  = (const float*)d_in[4];
  const float* Wh2  = (const float*)d_in[5];
  const float* bh2  = (const float*)d_in[6];
  const float* w0   = (const float*)d_in[7];
  const float* w1   = (const float*)d_in[8];
  const float* l1W  = (const float*)d_in[9];
  const float* l1b  = (const float*)d_in[10];
  const float* l2W  = (const float*)d_in[11];
  const float* l2b  = (const float*)d_in[12];
  const float* Wout = (const float*)d_in[13];
  const float* bout = (const float*)d_in[14];

  char* ws = (char*)d_ws;
  const size_t MB = 1048576ull;
  unsigned short* geomb = (unsigned short*)(ws);
  unsigned short* x2b   = (unsigned short*)(ws);
  unsigned short* x1b   = (unsigned short*)(ws + 32 * MB);
  float*  x3  = (float*)(ws + 32 * MB);
  float2* S0  = (float2*)(ws + 40 * MB);
  float2* S1  = (float2*)(ws + 56 * MB);
  float2* Ap  = (float2*)(ws + 72 * MB);
  float2* Am  = (float2*)(ws + 72 * MB + 512);
  float2* b2c = (float2*)(ws + 72 * MB + 1024);
  float2* Q   = (float2*)(ws + 72 * MB + 1536);
  unsigned short* Winb = (unsigned short*)(ws + 96 * MB);
  unsigned short* Wh1b = (unsigned short*)(ws + 97 * MB);
  unsigned short* Wh2b = (unsigned short*)(ws + 98 * MB);

  f32_to_bf16_k<<<16384, 256, 0, stream>>>(geom, geomb, 4194304);
  f32_to_bf16_k<<<512, 256, 0, stream>>>(Win, Winb, 131072);
  f32_to_bf16_k<<<512, 256, 0, stream>>>(Wh1, Wh1b, 131072);
  f32_to_bf16_k<<<32, 256, 0, stream>>>(Wh2, Wh2b, 8192);

  gemm_async<128,128,64,64,unsigned short><<<dim3(256, 8), 256, 0, stream>>>(
      geomb, Winb, bin, x1b, 32768, 1024, 512);
  gemm_async<128,128,64,64,unsigned short><<<dim3(256, 4), 256, 0, stream>>>(
      x1b, Wh1b, bh1, x2b, 32768, 512, 1024);
  gemm_async<128, 64,64,32,float><<<dim3(256, 1), 256, 0, stream>>>(
      x2b, Wh2b, bh2, x3, 32768, 64, 512);

  precompute<<<17, 256, 0, stream>>>(w0, w1, l2W, l2b, Ap, Am, Q, b2c);
  dft64_rows<<<512, 256, 0, stream>>>(x3, S0);
  fft_stage1<-1><<<512, 256, 0, stream>>>(S0, S1);
  fft_stage2<-1, false><<<512, 256, 0, stream>>>(S1, S0);
  pw_lin<<<1024, 256, 0, stream>>>(S0, Ap, Am, l1W, l1b, Q, b2c, S1);
  fft_stage1<1><<<512, 256, 0, stream>>>(S1, S0);
  fft_stage2<1, true><<<512, 256, 0, stream>>>(S0, S1);
  if (out_size >= 8388608) {
    final_out<1><<<512, 256, 0, stream>>>(S1, Wout, bout, (float*)d_out);
  } else {
    final_out<0><<<512, 256, 0, stream>>>(S1, Wout, bout, (float*)d_out);
  }
}